// Round 1
// 247.566 us; speedup vs baseline: 1.1040x; 1.1040x over previous
//
#include <hip/hip_runtime.h>

// Problem constants: B=1, L=320, D=128, H=4, DH=32
#define LQ 320
#define NSEQ 320
#define NROWS (NSEQ*LQ)   // 102400
#define DDIM 128
#define NH 4
#define DHD 32
#define LN_EPS 1e-5f
// 1/sqrt(32) * log2(e): folded into q so QK^T scores are in log2 domain
#define QSC2 0.25508652025545527f

typedef __bf16 bf16x8 __attribute__((ext_vector_type(8)));
typedef float f32x4 __attribute__((ext_vector_type(4)));
union FragU { unsigned int u[4]; bf16x8 v; };

// key-compaction tables (mask is over keys, shared by all rows)
__device__ __align__(16) int g_pos[LQ];   // kept key i -> compact slot, else -1
__device__ int g_cnt;                     // number of kept keys

__device__ inline unsigned short f2bf(float f) {
    unsigned int u = __float_as_uint(f);
    u += 0x7fffu + ((u >> 16) & 1u);
    return (unsigned short)(u >> 16);
}
__device__ inline unsigned int pack2(float a, float b) {
    return (unsigned int)f2bf(a) | ((unsigned int)f2bf(b) << 16);
}

// =====================================================================
// K_PRE: mask prefix-scan -> g_pos/g_cnt; zero-fill compaction pad
// regions of kws (rows [cnt, ceil16(cnt))) and vws (cols [cnt,
// ceil32(cnt))) per (n,h) so padded MFMA operands are finite zeros.
// Grid 1280 (one per n*NH+h), block 320 (one thread per key).
// =====================================================================
__global__ __launch_bounds__(320) void k_pre(
    const int* __restrict__ mask,
    unsigned short* __restrict__ kws, unsigned short* __restrict__ vws)
{
    __shared__ int sm[LQ];
    const int tid = threadIdx.x;       // 0..319
    const int nh = blockIdx.x;         // 0..1279
    const int m = (mask[tid] > 0) ? 1 : 0;
    sm[tid] = m;
    __syncthreads();
    // Hillis-Steele inclusive scan (9 steps)
    #pragma unroll 1
    for (int off = 1; off < LQ; off <<= 1) {
        const int a = sm[tid];
        const int b = (tid >= off) ? sm[tid - off] : 0;
        __syncthreads();
        sm[tid] = a + b;
        __syncthreads();
    }
    const int cnt = sm[LQ - 1];

    if (nh == 0) {
        g_pos[tid] = m ? (sm[tid] - 1) : -1;
        if (tid == 0) g_cnt = cnt;
    }

    const int PT  = (cnt + 15) & ~15;
    const int C32 = (cnt + 31) & ~31;

    // zero K pad rows [cnt, PT)
    unsigned short* kbase = kws + (size_t)nh * LQ * DHD;
    const int nkr = PT - cnt;          // 0..15
    #pragma unroll 1
    for (int idx = tid; idx < nkr * DHD; idx += 320) {
        const int r = idx >> 5, d = idx & 31;
        kbase[(size_t)(cnt + r) * DHD + d] = 0;
    }
    // zero V pad cols [cnt, C32) for all 32 d
    const int nvc = C32 - cnt;         // 0..31
    if (nvc > 0) {
        unsigned short* vb = vws + (size_t)nh * DHD * LQ;
        #pragma unroll 1
        for (int idx = tid; idx < DHD * nvc; idx += 320) {
            const int d = idx / nvc, c = idx - d * nvc;
            vb[(size_t)d * LQ + cnt + c] = 0;
        }
    }
}

// =====================================================================
// K0: LayerNorm -> zn bf16 [row][128] in ws. Grid 1600, block 256.
// =====================================================================
__global__ __launch_bounds__(256) void k0_ln(
    const float* __restrict__ z, const float* __restrict__ ln_g, const float* __restrict__ ln_b,
    unsigned int* __restrict__ znws)
{
    const int tid = threadIdx.x;
    const int rowbase = blockIdx.x * 64;
    const int lane = tid & 63;
    const int wid = tid >> 6;
    const float g0 = ln_g[2 * lane], g1 = ln_g[2 * lane + 1];
    const float bb0 = ln_b[2 * lane], bb1 = ln_b[2 * lane + 1];
    #pragma unroll 1
    for (int r = wid; r < 64; r += 4) {
        const int row = rowbase + r;
        const float2 v = *(const float2*)(z + (size_t)row * DDIM + 2 * lane);
        float s = v.x + v.y;
        float s2 = v.x * v.x + v.y * v.y;
        #pragma unroll
        for (int off = 32; off > 0; off >>= 1) {
            s  += __shfl_xor(s, off, 64);
            s2 += __shfl_xor(s2, off, 64);
        }
        const float mu = s * (1.0f / 128.0f);
        const float var = s2 * (1.0f / 128.0f) - mu * mu;
        const float rs = rsqrtf(var + LN_EPS);
        znws[(size_t)row * 64 + lane] =
            pack2((v.x - mu) * rs * g0 + bb0, (v.y - mu) * rs * g1 + bb1);
    }
}

// =====================================================================
// K1: QKV GEMM, 3-way N-split. Grid 2400 (sect = bx%3, m = bx/3), block 256.
// zn A-frags direct from global; LDS = W chunk only. Epilogue: C -> tr
// LDS -> coalesced stores. NEW: K rows stored compacted at g_pos[i]
// (vectorized), V stored compacted via conditional element scatter.
// q prescaled by 1/sqrt(DH)*log2e; v stored transposed.
// =====================================================================
__global__ __launch_bounds__(256) void k1_qkv(
    const unsigned short* __restrict__ znws, const float* __restrict__ w_qkv,
    const float* __restrict__ b_qkv,
    unsigned short* __restrict__ qws, unsigned short* __restrict__ kws,
    unsigned short* __restrict__ vws)
{
    __shared__ unsigned int wlds[128 * 68];   // 34816 B; later reused as tr
    const int tid = threadIdx.x;
    const int bx = blockIdx.x;
    const int sect = bx % 3;          // 0=q 1=k 2=v
    const int mbase = (bx / 3) * 128;
    const int lane = tid & 63;
    const int wid = tid >> 6;
    const int qn = lane & 15, gd = lane >> 4;

    // stage W chunk (fp32 -> bf16): rows sect*128..+127
    const float4* wp4 = (const float4*)w_qkv;
    #pragma unroll 1
    for (int idx = tid; idx < 128 * 32; idx += 256) {
        const int row = idx >> 5, c4 = idx & 31;
        const float4 w4 = wp4[(size_t)(sect * 128 + row) * 32 + c4];
        wlds[row * 68 + 2 * c4]     = pack2(w4.x, w4.y);
        wlds[row * 68 + 2 * c4 + 1] = pack2(w4.z, w4.w);
    }
    __syncthreads();

    const f32x4 zero4 = {0.f, 0.f, 0.f, 0.f};
    f32x4 acc[2][8];
    #pragma unroll
    for (int rg = 0; rg < 2; ++rg)
        #pragma unroll
        for (int nt = 0; nt < 8; ++nt) acc[rg][nt] = zero4;

    #pragma unroll
    for (int kt = 0; kt < 4; ++kt) {
        FragU af[2];
        #pragma unroll
        for (int rg = 0; rg < 2; ++rg)
            af[rg].v = *(const bf16x8*)&znws[
                (size_t)(mbase + wid * 32 + rg * 16 + qn) * DDIM + kt * 32 + gd * 8];
        #pragma unroll
        for (int nt = 0; nt < 8; ++nt) {
            FragU bf;
            bf.v = *(const bf16x8*)&wlds[(nt * 16 + qn) * 68 + 16 * kt + 4 * gd];
            #pragma unroll
            for (int rg = 0; rg < 2; ++rg)
                acc[rg][nt] = __builtin_amdgcn_mfma_f32_16x16x32_bf16(af[rg].v, bf.v, acc[rg][nt], 0, 0, 0);
        }
    }

    float bq[8];
    #pragma unroll
    for (int nt = 0; nt < 8; ++nt) bq[nt] = b_qkv[sect * 128 + nt * 16 + qn];
    const float sc = (sect == 0) ? QSC2 : 1.0f;

    __syncthreads();   // all waves done reading wlds
    unsigned short* tr = (unsigned short*)wlds;  // [128][132] (q/k: [row][col], v: [col][row])

    #pragma unroll
    for (int rg = 0; rg < 2; ++rg) {
        #pragma unroll
        for (int r = 0; r < 4; ++r) {
            const int row = wid * 32 + rg * 16 + 4 * gd + r;
            #pragma unroll
            for (int nt = 0; nt < 8; ++nt) {
                const int col = nt * 16 + qn;
                const unsigned short val = f2bf((acc[rg][nt][r] + bq[nt]) * sc);
                if (sect < 2) tr[row * 132 + col] = val;
                else          tr[col * 132 + row] = val;
            }
        }
    }
    __syncthreads();

    // wave-per-head coalesced stores (head h = wid)
    if (sect < 2) {
        unsigned short* dst = (sect == 0) ? qws : kws;
        #pragma unroll 1
        for (int k16 = 0; k16 < 16; ++k16) {
            const int o2 = lane * 4 + k16 * 256;     // over [128 i][32 d]
            const int i_loc = o2 >> 5, d = o2 & 31;
            const int grow = mbase + i_loc;
            const int n = grow / LQ;
            const int i = grow - n * LQ;
            const ushort4 val = *(const ushort4*)&tr[i_loc * 132 + wid * 32 + d];
            int idst = i;
            if (sect == 1) idst = g_pos[i];          // compacted K row
            if (idst >= 0)
                *(ushort4*)&dst[(((size_t)(n * NH + wid) * LQ + idst)) * DHD + d] = val;
        }
    } else {
        #pragma unroll 1
        for (int k16 = 0; k16 < 16; ++k16) {
            const int o2 = lane * 4 + k16 * 256;     // over [32 d][128 i]
            const int d = o2 >> 7, i_loc = o2 & 127;
            const int grow = mbase + i_loc;
            const int n = grow / LQ;
            const int i = grow - n * LQ;             // i % 4 == 0
            const ushort4 val = *(const ushort4*)&tr[(wid * 32 + d) * 132 + i_loc];
            unsigned short* vdst = vws + ((size_t)(n * NH + wid) * DHD + d) * LQ;
            const int4 p4 = *(const int4*)&g_pos[i]; // 16B-aligned
            if (p4.x >= 0) vdst[p4.x] = val.x;
            if (p4.y >= 0) vdst[p4.y] = val.y;
            if (p4.z >= 0) vdst[p4.z] = val.z;
            if (p4.w >= 0) vdst[p4.w] = val.w;
        }
    }
}

// =====================================================================
// K2: MFMA attention over COMPACTED keys. Grid 6400: block = (n,h,
// query-fifth); 256 thr (4 waves), one 16-query tile per wave.
// Live key tiles = ceil(cnt/16) (~10 for cnt~160) instead of 20:
// QK MFMA, exp2, packing, bpermute, V loads and K staging all halve.
// Dead tiles: wave-uniform scalar skip, st=0. Boundary tile: -1e30
// folded into MFMA C via 4 compares (bias LDS + mask load dropped).
// Online softmax across chunks of 10 tiles (usually 1 chunk).
// LDS: kT [<=320][20] (<=25.6KB). V frags direct from global (L2).
// =====================================================================
#define KSTR 20
__global__ __launch_bounds__(256, 4) void k2_attn_mfma(
    const unsigned short* __restrict__ qws, const unsigned short* __restrict__ kws,
    const unsigned short* __restrict__ vtws, unsigned short* __restrict__ ows)
{
    __shared__ unsigned int kT[LQ * KSTR];        // 25.6 KB max
    const int tid = threadIdx.x;
    const int bx = blockIdx.x;
    const int nh = bx / 5;
    const int qs = bx - nh * 5;
    const int lane = tid & 63;
    const int wid = tid >> 6;
    const int qn = lane & 15;
    const int gd = lane >> 4;

    const int cnt = __builtin_amdgcn_readfirstlane(g_cnt);
    const int PT  = (cnt + 15) & ~15;      // live rows (global-zero-padded)
    const int NCH = (PT + 159) / 160;      // chunks of 10 tiles (1 or 2)

    const uint4* kp4 = (const uint4*)(kws + (size_t)nh * LQ * DHD);
    #pragma unroll 1
    for (int idx = tid; idx < PT * 4; idx += 256) {
        const int r = idx >> 2, c4 = idx & 3;
        *(uint4*)&kT[r * KSTR + 4 * c4] = kp4[idx];
    }
    __syncthreads();

    const f32x4 zero4 = {0.f, 0.f, 0.f, 0.f};
    const int alo = (((gd & 1) << 5) | qn) << 2;
    const int ahi = alo + 64;
    const bool hiT = (gd >= 2);
    const int n = nh >> 2, h = nh & 3;
    const unsigned short* vbase = vtws + (size_t)nh * DHD * LQ;  // [32][320] bf16, compacted cols

    const int qt = qs * 4 + wid;

    FragU qf;
    qf.v = *(const bf16x8*)(qws + ((size_t)nh * LQ + qt * 16 + qn) * DHD + 8 * gd);

    f32x4 o0 = zero4, o1 = zero4;
    float m_run = -1e30f;
    float l_run = 0.f;

    #pragma unroll 1
    for (int ch = 0; ch < NCH; ++ch) {
        const int tb = ch * 10;

        f32x4 st[10];
        #pragma unroll
        for (int kt = 0; kt < 10; ++kt) {
            const int ktg = tb + kt;
            if (ktg * 16 < cnt) {                      // live tile (uniform)
                FragU kf;
                const uint4 kv = *(const uint4*)&kT[(ktg * 16 + qn) * KSTR + 4 * gd];
                kf.u[0] = kv.x; kf.u[1] = kv.y; kf.u[2] = kv.z; kf.u[3] = kv.w;
                f32x4 c0 = zero4;
                if ((ktg + 1) * 16 > cnt) {            // boundary tile: fold -inf bias
                    const int jb = ktg * 16 + 4 * gd;
                    #pragma unroll
                    for (int r = 0; r < 4; ++r)
                        c0[r] = (jb + r < cnt) ? 0.f : -1e30f;
                }
                st[kt] = __builtin_amdgcn_mfma_f32_16x16x32_bf16(kf.v, qf.v, c0, 0, 0, 0);
            }
        }

        float mh = -1e30f;
        #pragma unroll
        for (int kt = 0; kt < 10; ++kt)
            if ((tb + kt) * 16 < cnt)
                mh = fmaxf(mh, fmaxf(fmaxf(st[kt][0], st[kt][1]), fmaxf(st[kt][2], st[kt][3])));
        mh = fmaxf(mh, __shfl_xor(mh, 16, 64));
        mh = fmaxf(mh, __shfl_xor(mh, 32, 64));
        const float m_new = fmaxf(m_run, mh);
        const float scl = __builtin_amdgcn_exp2f(m_run - m_new);
        m_run = m_new;
        l_run *= scl;
        o0 *= scl;
        o1 *= scl;

        #pragma unroll
        for (int kt = 0; kt < 10; ++kt) {
            if ((tb + kt) * 16 < cnt) {
                st[kt][0] = __builtin_amdgcn_exp2f(st[kt][0] - m_new);
                st[kt][1] = __builtin_amdgcn_exp2f(st[kt][1] - m_new);
                st[kt][2] = __builtin_amdgcn_exp2f(st[kt][2] - m_new);
                st[kt][3] = __builtin_amdgcn_exp2f(st[kt][3] - m_new);
                l_run += st[kt][0] + st[kt][1] + st[kt][2] + st[kt][3];
            } else {
                st[kt] = zero4;                        // P = 0 for dead keys
            }
        }

        #pragma unroll
        for (int kc = 0; kc < 5; ++kc) {
            if ((tb + 2 * kc) * 16 < cnt) {            // live pair (uniform)
                const int t0 = 2 * kc, t1 = 2 * kc + 1;
                const unsigned int p01a = pack2(st[t0][0], st[t0][1]);
                const unsigned int p23a = pack2(st[t0][2], st[t0][3]);
                const unsigned int p01b = pack2(st[t1][0], st[t1][1]);
                const unsigned int p23b = pack2(st[t1][2], st[t1][3]);
                FragU pa;
                {
                    const int a0 = __builtin_amdgcn_ds_bpermute(alo, (int)p01a);
                    const int b0 = __builtin_amdgcn_ds_bpermute(alo, (int)p01b);
                    const int a1 = __builtin_amdgcn_ds_bpermute(alo, (int)p23a);
                    const int b1 = __builtin_amdgcn_ds_bpermute(alo, (int)p23b);
                    const int a2 = __builtin_amdgcn_ds_bpermute(ahi, (int)p01a);
                    const int b2 = __builtin_amdgcn_ds_bpermute(ahi, (int)p01b);
                    const int a3 = __builtin_amdgcn_ds_bpermute(ahi, (int)p23a);
                    const int b3 = __builtin_amdgcn_ds_bpermute(ahi, (int)p23b);
                    pa.u[0] = (unsigned int)(hiT ? b0 : a0);
                    pa.u[1] = (unsigned int)(hiT ? b1 : a1);
                    pa.u[2] = (unsigned int)(hiT ? b2 : a2);
                    pa.u[3] = (unsigned int)(hiT ? b3 : a3);
                }
                FragU bv0, bv1;
                const int koff = ch * 160 + 32 * kc + 8 * gd;
                bv0.v = *(const bf16x8*)(vbase + (0 * 16 + qn) * LQ + koff);
                bv1.v = *(const bf16x8*)(vbase + (1 * 16 + qn) * LQ + koff);
                o0 = __builtin_amdgcn_mfma_f32_16x16x32_bf16(pa.v, bv0.v, o0, 0, 0, 0);
                o1 = __builtin_amdgcn_mfma_f32_16x16x32_bf16(pa.v, bv1.v, o1, 0, 0, 0);
            }
        }
    }

    l_run += __shfl_xor(l_run, 16, 64);
    l_run += __shfl_xor(l_run, 32, 64);
    const float inv = 1.0f / l_run;

    #pragma unroll
    for (int r = 0; r < 4; ++r) {
        const int qg = qt * 16 + 4 * gd + r;
        unsigned short* orow = ows + ((size_t)(n * LQ + qg)) * DDIM + h * DHD + qn;
        orow[0]  = f2bf(o0[r] * inv);
        orow[16] = f2bf(o1[r] * inv);
    }
}

// =====================================================================
// K3: out projection + residual, MFMA. Grid 800, block 256.
// =====================================================================
__global__ __launch_bounds__(256) void k3_out(
    const unsigned short* __restrict__ ows, const float* __restrict__ w_out,
    const float* __restrict__ b_out, const float* __restrict__ z,
    float* __restrict__ out)
{
    __shared__ unsigned int wlds[128 * 68];
    const int tid = threadIdx.x;
    const int mbase = blockIdx.x * 128;
    const int lane = tid & 63;
    const int wid = tid >> 6;
    const int qn = lane & 15, gd = lane >> 4;

    const float4* wp4 = (const float4*)w_out;
    #pragma unroll 1
    for (int idx = tid; idx < 128 * 32; idx += 256) {
        const int row = idx >> 5, c4 = idx & 31;
        const float4 w4 = wp4[idx];
        wlds[row * 68 + 2 * c4]     = pack2(w4.x, w4.y);
        wlds[row * 68 + 2 * c4 + 1] = pack2(w4.z, w4.w);
    }
    __syncthreads();

    const f32x4 zero4 = {0.f, 0.f, 0.f, 0.f};
    f32x4 acc[2][8];
    #pragma unroll
    for (int rg = 0; rg < 2; ++rg)
        #pragma unroll
        for (int nt = 0; nt < 8; ++nt) acc[rg][nt] = zero4;

    #pragma unroll
    for (int kt = 0; kt < 4; ++kt) {
        FragU af[2];
        #pragma unroll
        for (int rg = 0; rg < 2; ++rg)
            af[rg].v = *(const bf16x8*)&ows[
                (size_t)(mbase + wid * 32 + rg * 16 + qn) * DDIM + kt * 32 + gd * 8];
        #pragma unroll
        for (int nt = 0; nt < 8; ++nt) {
            FragU bf;
            bf.v = *(const bf16x8*)&wlds[(nt * 16 + qn) * 68 + 16 * kt + 4 * gd];
            #pragma unroll
            for (int rg = 0; rg < 2; ++rg)
                acc[rg][nt] = __builtin_amdgcn_mfma_f32_16x16x32_bf16(af[rg].v, bf.v, acc[rg][nt], 0, 0, 0);
        }
    }

    float bb[8];
    #pragma unroll
    for (int nt = 0; nt < 8; ++nt) bb[nt] = b_out[nt * 16 + qn];

    #pragma unroll
    for (int rg = 0; rg < 2; ++rg) {
        #pragma unroll
        for (int r = 0; r < 4; ++r) {
            const int grow = mbase + wid * 32 + rg * 16 + 4 * gd + r;
            const float* zr = z + (size_t)grow * DDIM;
            float* outr = out + (size_t)grow * DDIM;
            #pragma unroll
            for (int nt = 0; nt < 8; ++nt) {
                const int cg = nt * 16 + qn;
                outr[cg] = acc[rg][nt][r] + bb[nt] + zr[cg];
            }
        }
    }
}

extern "C" void kernel_launch(void* const* d_in, const int* in_sizes, int n_in,
                              void* d_out, int out_size, void* d_ws, size_t ws_size,
                              hipStream_t stream) {
    const float* z     = (const float*)d_in[0];
    const int*   mask  = (const int*)d_in[1];
    const float* ln_g  = (const float*)d_in[2];
    const float* ln_b  = (const float*)d_in[3];
    const float* w_qkv = (const float*)d_in[4];
    const float* b_qkv = (const float*)d_in[5];
    const float* w_out = (const float*)d_in[6];
    const float* b_out = (const float*)d_in[7];
    float* out = (float*)d_out;

    unsigned short* ws = (unsigned short*)d_ws;
    const size_t qE = (size_t)NSEQ * NH * LQ * DHD;  // 13,107,200
    unsigned short* qws = ws;
    unsigned short* kws = qws + qE;
    unsigned short* vws = kws + qE;
    unsigned short* shared_rgn = vws + qE;           // NROWS*DDIM bf16
    unsigned int*   znws = (unsigned int*)shared_rgn;
    unsigned short* ows  = shared_rgn;

    hipLaunchKernelGGL(k_pre, dim3(NSEQ * NH), dim3(320), 0, stream,
                       mask, kws, vws);
    hipLaunchKernelGGL(k0_ln, dim3(NROWS / 64), dim3(256), 0, stream,
                       z, ln_g, ln_b, znws);
    hipLaunchKernelGGL(k1_qkv, dim3(2400), dim3(256), 0, stream,
                       (const unsigned short*)znws, w_qkv, b_qkv, qws, kws, vws);
    hipLaunchKernelGGL(k2_attn_mfma, dim3(6400), dim3(256), 0, stream,
                       qws, kws, vws, ows);
    hipLaunchKernelGGL(k3_out, dim3(800), dim3(256), 0, stream,
                       ows, w_out, b_out, z, out);
}

// Round 2
// 242.690 us; speedup vs baseline: 1.1262x; 1.0201x over previous
//
#include <hip/hip_runtime.h>

// Problem constants: B=1, L=320, D=128, H=4, DH=32
#define LQ 320
#define NSEQ 320
#define NROWS (NSEQ*LQ)   // 102400
#define DDIM 128
#define NH 4
#define DHD 32
#define LN_EPS 1e-5f
// 1/sqrt(32) * log2(e): folded into q so QK^T scores are in log2 domain
#define QSC2 0.25508652025545527f

typedef __bf16 bf16x8 __attribute__((ext_vector_type(8)));
typedef float f32x4 __attribute__((ext_vector_type(4)));
union FragU { unsigned int u[4]; bf16x8 v; };

// key-compaction tables (mask is over keys, shared by all rows)
__device__ int g_inv[LQ];     // compact slot -> key position (pad slots -> 0)
__device__ int g_cnt;         // number of kept keys
// pre-converted bf16 weights: rows 0-383 = w_qkv, rows 384-511 = w_out
__device__ __align__(16) unsigned short g_wbf[512 * DDIM];

__device__ inline unsigned short f2bf(float f) {
    unsigned int u = __float_as_uint(f);
    u += 0x7fffu + ((u >> 16) & 1u);
    return (unsigned short)(u >> 16);
}
__device__ inline unsigned int pack2(float a, float b) {
    return (unsigned int)f2bf(a) | ((unsigned int)f2bf(b) << 16);
}

// =====================================================================
// K0: LayerNorm -> zn bf16 [row][128]. Grid 1600, block 256.
// Side jobs folded in (k_pre deleted):
//  - block 0, wave 0: mask scan -> g_inv / g_cnt
//  - blocks 1..64: w_qkv + w_out fp32 -> bf16 into g_wbf (once, globally)
// =====================================================================
__global__ __launch_bounds__(256) void k0_ln(
    const float* __restrict__ z, const float* __restrict__ ln_g, const float* __restrict__ ln_b,
    unsigned int* __restrict__ znws, const int* __restrict__ mask,
    const float* __restrict__ w_qkv, const float* __restrict__ w_out)
{
    const int tid = threadIdx.x;
    const int bx = blockIdx.x;
    const int rowbase = bx * 64;
    const int lane = tid & 63;
    const int wid = tid >> 6;

    if (bx == 0) {
        if (tid < 64) {
            int carry = 0;
            #pragma unroll 1
            for (int c = 0; c < 5; ++c) {
                const int i = c * 64 + tid;
                const int m = (mask[i] > 0) ? 1 : 0;
                int v = m;
                #pragma unroll
                for (int off = 1; off < 64; off <<= 1) {
                    const int o = __shfl_up(v, off, 64);
                    if (tid >= off) v += o;
                }
                v += carry;
                if (m) g_inv[v - 1] = i;
                carry = __shfl(v, 63, 64);
            }
            if (tid == 0) g_cnt = carry;
            for (int s = carry + tid; s < LQ; s += 64) g_inv[s] = 0;  // pad slots
        }
    } else if (bx <= 64) {
        const int idx = (bx - 1) * 256 + tid;   // 0..16383, covers 512*128 fp32
        const float4 w4 = (idx < 12288) ? ((const float4*)w_qkv)[idx]
                                        : ((const float4*)w_out)[idx - 12288];
        uint2 val;
        val.x = pack2(w4.x, w4.y);
        val.y = pack2(w4.z, w4.w);
        ((uint2*)g_wbf)[idx] = val;
    }

    const float g0 = ln_g[2 * lane], g1 = ln_g[2 * lane + 1];
    const float bb0 = ln_b[2 * lane], bb1 = ln_b[2 * lane + 1];
    #pragma unroll 1
    for (int r = wid; r < 64; r += 4) {
        const int row = rowbase + r;
        const float2 v = *(const float2*)(z + (size_t)row * DDIM + 2 * lane);
        float s = v.x + v.y;
        float s2 = v.x * v.x + v.y * v.y;
        #pragma unroll
        for (int off = 32; off > 0; off >>= 1) {
            s  += __shfl_xor(s, off, 64);
            s2 += __shfl_xor(s2, off, 64);
        }
        const float mu = s * (1.0f / 128.0f);
        const float var = s2 * (1.0f / 128.0f) - mu * mu;
        const float rs = rsqrtf(var + LN_EPS);
        znws[(size_t)row * 64 + lane] =
            pack2((v.x - mu) * rs * g0 + bb0, (v.y - mu) * rs * g1 + bb1);
    }
}

// =====================================================================
// K1: QKV GEMM, 3-way N-split. Grid 2400 (sect = bx%3, m = bx/3), block 256.
// Round-2: B-frags DIRECT from pre-converted bf16 g_wbf (no W staging,
// no conversion, one fewer barrier). K/V sections process COMPACT rows
// only (gather src rows via g_inv): 2/3 GEMM work, ~800 blocks exit at
// once, and V stores are ushort4-vectorized again (slot == row index).
// Epilogue: two 64-row transpose phases through 17.4 KB LDS.
// Layouts: q [nh][320][32]; k [nh][PT16 packed][32] (plane stride 320*32);
// v [nh][32 d][CP8 packed] (plane stride 32*320). Pad rows hold finite
// garbage (src row 0) -- k2's bias/skip logic zeroes their P.
// =====================================================================
__global__ __launch_bounds__(256, 4) void k1_qkv(
    const unsigned short* __restrict__ znws, const float* __restrict__ b_qkv,
    unsigned short* __restrict__ qws, unsigned short* __restrict__ kws,
    unsigned short* __restrict__ vws)
{
    __shared__ unsigned short tr[8704];  // 17408 B: qk view [64][132], v view [128][68]
    const int tid = threadIdx.x;
    const int bx = blockIdx.x;
    const int sect = bx % 3;          // 0=q 1=k 2=v
    const int mbase = (bx / 3) * 128;
    const int lane = tid & 63;
    const int wid = tid >> 6;
    const int qn = lane & 15, gd = lane >> 4;

    const int cnt = __builtin_amdgcn_readfirstlane(g_cnt);
    const int PT16 = (cnt + 15) & ~15;
    const int CP8  = (cnt + 7) & ~7;
    const int stride = (sect == 0) ? LQ : ((sect == 1) ? PT16 : CP8);
    const int rows_total = NSEQ * stride;
    if (mbase >= rows_total) return;

    const int n0 = mbase / stride;
    const int s0 = mbase - n0 * stride;

    // A-frag source rows (compact gather for k/v sections)
    int arow[2];
    #pragma unroll
    for (int rg = 0; rg < 2; ++rg) {
        const int off = wid * 32 + rg * 16 + qn;
        int n = n0, s = s0 + off;
        while (s >= stride) { s -= stride; ++n; }
        int grow = n * LQ + ((sect == 0) ? s : g_inv[s]);
        if (mbase + off >= rows_total) grow = 0;     // guarded at store time
        arow[rg] = grow;
    }

    const f32x4 zero4 = {0.f, 0.f, 0.f, 0.f};
    f32x4 acc[2][8];
    #pragma unroll
    for (int rg = 0; rg < 2; ++rg)
        #pragma unroll
        for (int nt = 0; nt < 8; ++nt) acc[rg][nt] = zero4;

    #pragma unroll
    for (int kt = 0; kt < 4; ++kt) {
        FragU af[2];
        #pragma unroll
        for (int rg = 0; rg < 2; ++rg)
            af[rg].v = *(const bf16x8*)&znws[(size_t)arow[rg] * DDIM + kt * 32 + gd * 8];
        #pragma unroll
        for (int nt = 0; nt < 8; ++nt) {
            FragU bf;
            bf.v = *(const bf16x8*)&g_wbf[(size_t)(sect * 128 + nt * 16 + qn) * DDIM + kt * 32 + gd * 8];
            #pragma unroll
            for (int rg = 0; rg < 2; ++rg)
                acc[rg][nt] = __builtin_amdgcn_mfma_f32_16x16x32_bf16(af[rg].v, bf.v, acc[rg][nt], 0, 0, 0);
        }
    }

    float bq[8];
    #pragma unroll
    for (int nt = 0; nt < 8; ++nt) bq[nt] = b_qkv[sect * 128 + nt * 16 + qn];
    const float sc = (sect == 0) ? QSC2 : 1.0f;

    // two-phase transpose epilogue (rows [p*64, p*64+64) of the block tile)
    #pragma unroll 1
    for (int p = 0; p < 2; ++p) {
        if ((wid >> 1) == p) {
            const int wl = wid & 1;
            #pragma unroll
            for (int rg = 0; rg < 2; ++rg) {
                #pragma unroll
                for (int r = 0; r < 4; ++r) {
                    const int lr = wl * 32 + rg * 16 + 4 * gd + r;   // 0..63
                    #pragma unroll
                    for (int nt = 0; nt < 8; ++nt) {
                        const int col = nt * 16 + qn;
                        const unsigned short val = f2bf((acc[rg][nt][r] + bq[nt]) * sc);
                        if (sect < 2) tr[lr * 132 + col] = val;
                        else          tr[col * 68 + lr] = val;
                    }
                }
            }
        }
        __syncthreads();

        if (sect < 2) {
            unsigned short* dst = (sect == 0) ? qws : kws;
            #pragma unroll 1
            for (int k8 = 0; k8 < 8; ++k8) {
                const int o2 = lane * 4 + k8 * 256;     // [64 rows][32 d] per head(wid)
                const int i_loc = o2 >> 5, d = o2 & 31;
                const int off = p * 64 + i_loc;
                if (mbase + off < rows_total) {
                    int n = n0, s = s0 + off;
                    while (s >= stride) { s -= stride; ++n; }
                    const ushort4 val = *(const ushort4*)&tr[i_loc * 132 + wid * 32 + d];
                    *(ushort4*)&dst[((size_t)(n * NH + wid) * LQ + s) * DHD + d] = val;
                }
            }
        } else {
            #pragma unroll 1
            for (int k8 = 0; k8 < 8; ++k8) {
                const int o2 = lane * 4 + k8 * 256;     // [32 d][64 rows]
                const int d = o2 >> 6, i_loc = o2 & 63;
                const int off = p * 64 + i_loc;
                if (mbase + off < rows_total) {
                    int n = n0, s = s0 + off;
                    while (s >= stride) { s -= stride; ++n; }
                    const ushort4 val = *(const ushort4*)&tr[(wid * 32 + d) * 68 + i_loc];
                    *(ushort4*)&vws[(size_t)(n * NH + wid) * (DHD * LQ) + d * CP8 + s] = val;
                }
            }
        }
        if (p == 0) __syncthreads();
    }
}

// =====================================================================
// K2: MFMA attention over COMPACTED keys. Grid 6400: block = (n,h,
// query-fifth); 256 thr (4 waves), one 16-query tile per wave.
// Live key tiles = ceil(cnt/16); dead tiles skipped (uniform branch);
// boundary tile folds -1e30 into MFMA C. V now has per-d row stride CP8.
// Pad K/V rows contain finite garbage; their P is exactly 0.
// =====================================================================
#define KSTR 20
__global__ __launch_bounds__(256, 4) void k2_attn_mfma(
    const unsigned short* __restrict__ qws, const unsigned short* __restrict__ kws,
    const unsigned short* __restrict__ vtws, unsigned short* __restrict__ ows)
{
    __shared__ unsigned int kT[LQ * KSTR];        // 25.6 KB max
    const int tid = threadIdx.x;
    const int bx = blockIdx.x;
    const int nh = bx / 5;
    const int qs = bx - nh * 5;
    const int lane = tid & 63;
    const int wid = tid >> 6;
    const int qn = lane & 15;
    const int gd = lane >> 4;

    const int cnt = __builtin_amdgcn_readfirstlane(g_cnt);
    const int PT  = (cnt + 15) & ~15;      // live packed K rows
    const int CP8 = (cnt + 7) & ~7;        // V col stride
    const int NCH = (PT + 159) / 160;      // chunks of 10 tiles (1 or 2)

    const uint4* kp4 = (const uint4*)(kws + (size_t)nh * LQ * DHD);
    #pragma unroll 1
    for (int idx = tid; idx < PT * 4; idx += 256) {
        const int r = idx >> 2, c4 = idx & 3;
        *(uint4*)&kT[r * KSTR + 4 * c4] = kp4[idx];
    }
    __syncthreads();

    const f32x4 zero4 = {0.f, 0.f, 0.f, 0.f};
    const int alo = (((gd & 1) << 5) | qn) << 2;
    const int ahi = alo + 64;
    const bool hiT = (gd >= 2);
    const int n = nh >> 2, h = nh & 3;
    const unsigned short* vbase = vtws + (size_t)nh * DHD * LQ;  // [32 d][CP8] bf16

    const int qt = qs * 4 + wid;

    FragU qf;
    qf.v = *(const bf16x8*)(qws + ((size_t)nh * LQ + qt * 16 + qn) * DHD + 8 * gd);

    f32x4 o0 = zero4, o1 = zero4;
    float m_run = -1e30f;
    float l_run = 0.f;

    #pragma unroll 1
    for (int ch = 0; ch < NCH; ++ch) {
        const int tb = ch * 10;

        f32x4 st[10];
        #pragma unroll
        for (int kt = 0; kt < 10; ++kt) {
            const int ktg = tb + kt;
            if (ktg * 16 < cnt) {                      // live tile (uniform)
                FragU kf;
                const uint4 kv = *(const uint4*)&kT[(ktg * 16 + qn) * KSTR + 4 * gd];
                kf.u[0] = kv.x; kf.u[1] = kv.y; kf.u[2] = kv.z; kf.u[3] = kv.w;
                f32x4 c0 = zero4;
                if ((ktg + 1) * 16 > cnt) {            // boundary tile: fold -inf bias
                    const int jb = ktg * 16 + 4 * gd;
                    #pragma unroll
                    for (int r = 0; r < 4; ++r)
                        c0[r] = (jb + r < cnt) ? 0.f : -1e30f;
                }
                st[kt] = __builtin_amdgcn_mfma_f32_16x16x32_bf16(kf.v, qf.v, c0, 0, 0, 0);
            }
        }

        float mh = -1e30f;
        #pragma unroll
        for (int kt = 0; kt < 10; ++kt)
            if ((tb + kt) * 16 < cnt)
                mh = fmaxf(mh, fmaxf(fmaxf(st[kt][0], st[kt][1]), fmaxf(st[kt][2], st[kt][3])));
        mh = fmaxf(mh, __shfl_xor(mh, 16, 64));
        mh = fmaxf(mh, __shfl_xor(mh, 32, 64));
        const float m_new = fmaxf(m_run, mh);
        const float scl = __builtin_amdgcn_exp2f(m_run - m_new);
        m_run = m_new;
        l_run *= scl;
        o0 *= scl;
        o1 *= scl;

        #pragma unroll
        for (int kt = 0; kt < 10; ++kt) {
            if ((tb + kt) * 16 < cnt) {
                st[kt][0] = __builtin_amdgcn_exp2f(st[kt][0] - m_new);
                st[kt][1] = __builtin_amdgcn_exp2f(st[kt][1] - m_new);
                st[kt][2] = __builtin_amdgcn_exp2f(st[kt][2] - m_new);
                st[kt][3] = __builtin_amdgcn_exp2f(st[kt][3] - m_new);
                l_run += st[kt][0] + st[kt][1] + st[kt][2] + st[kt][3];
            } else {
                st[kt] = zero4;                        // P = 0 for dead keys
            }
        }

        #pragma unroll
        for (int kc = 0; kc < 5; ++kc) {
            if ((tb + 2 * kc) * 16 < cnt) {            // live pair (uniform)
                const int t0 = 2 * kc, t1 = 2 * kc + 1;
                const unsigned int p01a = pack2(st[t0][0], st[t0][1]);
                const unsigned int p23a = pack2(st[t0][2], st[t0][3]);
                const unsigned int p01b = pack2(st[t1][0], st[t1][1]);
                const unsigned int p23b = pack2(st[t1][2], st[t1][3]);
                FragU pa;
                {
                    const int a0 = __builtin_amdgcn_ds_bpermute(alo, (int)p01a);
                    const int b0 = __builtin_amdgcn_ds_bpermute(alo, (int)p01b);
                    const int a1 = __builtin_amdgcn_ds_bpermute(alo, (int)p23a);
                    const int b1 = __builtin_amdgcn_ds_bpermute(alo, (int)p23b);
                    const int a2 = __builtin_amdgcn_ds_bpermute(ahi, (int)p01a);
                    const int b2 = __builtin_amdgcn_ds_bpermute(ahi, (int)p01b);
                    const int a3 = __builtin_amdgcn_ds_bpermute(ahi, (int)p23a);
                    const int b3 = __builtin_amdgcn_ds_bpermute(ahi, (int)p23b);
                    pa.u[0] = (unsigned int)(hiT ? b0 : a0);
                    pa.u[1] = (unsigned int)(hiT ? b1 : a1);
                    pa.u[2] = (unsigned int)(hiT ? b2 : a2);
                    pa.u[3] = (unsigned int)(hiT ? b3 : a3);
                }
                FragU bv0, bv1;
                const int koff = ch * 160 + 32 * kc + 8 * gd;
                bv0.v = *(const bf16x8*)(vbase + (size_t)qn * CP8 + koff);
                bv1.v = *(const bf16x8*)(vbase + (size_t)(16 + qn) * CP8 + koff);
                o0 = __builtin_amdgcn_mfma_f32_16x16x32_bf16(pa.v, bv0.v, o0, 0, 0, 0);
                o1 = __builtin_amdgcn_mfma_f32_16x16x32_bf16(pa.v, bv1.v, o1, 0, 0, 0);
            }
        }
    }

    l_run += __shfl_xor(l_run, 16, 64);
    l_run += __shfl_xor(l_run, 32, 64);
    const float inv = 1.0f / l_run;

    #pragma unroll
    for (int r = 0; r < 4; ++r) {
        const int qg = qt * 16 + 4 * gd + r;
        unsigned short* orow = ows + ((size_t)(n * LQ + qg)) * DDIM + h * DHD + qn;
        orow[0]  = f2bf(o0[r] * inv);
        orow[16] = f2bf(o1[r] * inv);
    }
}

// =====================================================================
// K3: out projection + residual, MFMA. Grid 800, block 256.
// Round-2: w_out B-frags direct from g_wbf (rows 384-511) -> NO LDS,
// no staging phase, no barrier.
// =====================================================================
__global__ __launch_bounds__(256, 4) void k3_out(
    const unsigned short* __restrict__ ows,
    const float* __restrict__ b_out, const float* __restrict__ z,
    float* __restrict__ out)
{
    const int tid = threadIdx.x;
    const int mbase = blockIdx.x * 128;
    const int lane = tid & 63;
    const int wid = tid >> 6;
    const int qn = lane & 15, gd = lane >> 4;

    const f32x4 zero4 = {0.f, 0.f, 0.f, 0.f};
    f32x4 acc[2][8];
    #pragma unroll
    for (int rg = 0; rg < 2; ++rg)
        #pragma unroll
        for (int nt = 0; nt < 8; ++nt) acc[rg][nt] = zero4;

    #pragma unroll
    for (int kt = 0; kt < 4; ++kt) {
        FragU af[2];
        #pragma unroll
        for (int rg = 0; rg < 2; ++rg)
            af[rg].v = *(const bf16x8*)&ows[
                (size_t)(mbase + wid * 32 + rg * 16 + qn) * DDIM + kt * 32 + gd * 8];
        #pragma unroll
        for (int nt = 0; nt < 8; ++nt) {
            FragU bf;
            bf.v = *(const bf16x8*)&g_wbf[(size_t)(384 + nt * 16 + qn) * DDIM + kt * 32 + gd * 8];
            #pragma unroll
            for (int rg = 0; rg < 2; ++rg)
                acc[rg][nt] = __builtin_amdgcn_mfma_f32_16x16x32_bf16(af[rg].v, bf.v, acc[rg][nt], 0, 0, 0);
        }
    }

    float bb[8];
    #pragma unroll
    for (int nt = 0; nt < 8; ++nt) bb[nt] = b_out[nt * 16 + qn];

    #pragma unroll
    for (int rg = 0; rg < 2; ++rg) {
        #pragma unroll
        for (int r = 0; r < 4; ++r) {
            const int grow = mbase + wid * 32 + rg * 16 + 4 * gd + r;
            const float* zr = z + (size_t)grow * DDIM;
            float* outr = out + (size_t)grow * DDIM;
            #pragma unroll
            for (int nt = 0; nt < 8; ++nt) {
                const int cg = nt * 16 + qn;
                outr[cg] = acc[rg][nt][r] + bb[nt] + zr[cg];
            }
        }
    }
}

extern "C" void kernel_launch(void* const* d_in, const int* in_sizes, int n_in,
                              void* d_out, int out_size, void* d_ws, size_t ws_size,
                              hipStream_t stream) {
    const float* z     = (const float*)d_in[0];
    const int*   mask  = (const int*)d_in[1];
    const float* ln_g  = (const float*)d_in[2];
    const float* ln_b  = (const float*)d_in[3];
    const float* w_qkv = (const float*)d_in[4];
    const float* b_qkv = (const float*)d_in[5];
    const float* w_out = (const float*)d_in[6];
    const float* b_out = (const float*)d_in[7];
    float* out = (float*)d_out;

    unsigned short* ws = (unsigned short*)d_ws;
    const size_t qE = (size_t)NSEQ * NH * LQ * DHD;  // 13,107,200
    unsigned short* qws = ws;
    unsigned short* kws = qws + qE;
    unsigned short* vws = kws + qE;
    unsigned short* shared_rgn = vws + qE;           // NROWS*DDIM bf16
    unsigned int*   znws = (unsigned int*)shared_rgn;
    unsigned short* ows  = shared_rgn;

    hipLaunchKernelGGL(k0_ln, dim3(NROWS / 64), dim3(256), 0, stream,
                       z, ln_g, ln_b, znws, mask, w_qkv, w_out);
    hipLaunchKernelGGL(k1_qkv, dim3(2400), dim3(256), 0, stream,
                       (const unsigned short*)znws, b_qkv, qws, kws, vws);
    hipLaunchKernelGGL(k2_attn_mfma, dim3(6400), dim3(256), 0, stream,
                       qws, kws, vws, ows);
    hipLaunchKernelGGL(k3_out, dim3(800), dim3(256), 0, stream,
                       ows, b_out, z, out);
}

// Round 3
// 211.259 us; speedup vs baseline: 1.2938x; 1.1488x over previous
//
#include <hip/hip_runtime.h>

// Problem constants: B=1, L=320, D=128, H=4, DH=32
#define LQ 320
#define NSEQ 320
#define NROWS (NSEQ*LQ)   // 102400
#define DDIM 128
#define NH 4
#define DHD 32
#define LN_EPS 1e-5f
// 1/sqrt(32) * log2(e): folded into q so QK^T scores are in log2 domain
#define QSC2 0.25508652025545527f

typedef __bf16 bf16x8 __attribute__((ext_vector_type(8)));
typedef float f32x4 __attribute__((ext_vector_type(4)));
union FragU { unsigned int u[4]; bf16x8 v; };

// key-compaction tables (mask is over keys, shared by all rows)
__device__ int g_inv[LQ];     // compact slot -> key position (pad slots -> 0)
__device__ int g_cnt;         // number of kept keys
// pre-converted bf16 weights in MFMA FRAGMENT order:
// uint4 chunk cid = ((s4*4 + kt)*8 + nt)*64 + lane holds
// W row (s4*128 + nt*16 + (lane&15)), cols kt*32 + (lane>>4)*8 .. +7.
// s4: 0,1,2 = w_qkv q/k/v chunks, 3 = w_out.
__device__ __align__(16) unsigned short g_wbf[512 * DDIM];

__device__ inline unsigned short f2bf(float f) {
    unsigned int u = __float_as_uint(f);
    u += 0x7fffu + ((u >> 16) & 1u);
    return (unsigned short)(u >> 16);
}
__device__ inline unsigned int pack2(float a, float b) {
    return (unsigned int)f2bf(a) | ((unsigned int)f2bf(b) << 16);
}

// =====================================================================
// K0: LayerNorm -> zn bf16 [row][128]. Grid 1600, block 256.
// Side jobs: block 0 wave 0: mask scan -> g_inv / g_cnt;
// blocks 1..32: W fp32 -> bf16 into g_wbf in FRAGMENT order.
// =====================================================================
__global__ __launch_bounds__(256) void k0_ln(
    const float* __restrict__ z, const float* __restrict__ ln_g, const float* __restrict__ ln_b,
    unsigned int* __restrict__ znws, const int* __restrict__ mask,
    const float* __restrict__ w_qkv, const float* __restrict__ w_out)
{
    const int tid = threadIdx.x;
    const int bx = blockIdx.x;
    const int rowbase = bx * 64;
    const int lane = tid & 63;
    const int wid = tid >> 6;

    if (bx == 0) {
        if (tid < 64) {
            int carry = 0;
            #pragma unroll 1
            for (int c = 0; c < 5; ++c) {
                const int i = c * 64 + tid;
                const int m = (mask[i] > 0) ? 1 : 0;
                int v = m;
                #pragma unroll
                for (int off = 1; off < 64; off <<= 1) {
                    const int o = __shfl_up(v, off, 64);
                    if (tid >= off) v += o;
                }
                v += carry;
                if (m) g_inv[v - 1] = i;
                carry = __shfl(v, 63, 64);
            }
            if (tid == 0) g_cnt = carry;
            for (int s = carry + tid; s < LQ; s += 64) g_inv[s] = 0;  // pad slots
        }
    } else if (bx <= 32) {
        // fragment-order W conversion: one uint4 chunk per thread
        const int cid = (bx - 1) * 256 + tid;   // 0..8191
        const int l2  = cid & 63;
        const int nt  = (cid >> 6) & 7;
        const int kt  = (cid >> 9) & 3;
        const int s4  = cid >> 11;              // 0..3
        const int qn2 = l2 & 15, gd2 = l2 >> 4;
        const int row = s4 * 128 + nt * 16 + qn2;       // 0..511
        const float4* src4 = (s4 < 3) ? (const float4*)w_qkv : (const float4*)w_out;
        const int rloc = (s4 < 3) ? row : (row - 384);
        const int fi = rloc * 32 + kt * 8 + gd2 * 2;
        const float4 a = src4[fi];
        const float4 b = src4[fi + 1];
        uint4 val;
        val.x = pack2(a.x, a.y);
        val.y = pack2(a.z, a.w);
        val.z = pack2(b.x, b.y);
        val.w = pack2(b.z, b.w);
        ((uint4*)g_wbf)[cid] = val;
    }

    const float g0 = ln_g[2 * lane], g1 = ln_g[2 * lane + 1];
    const float bb0 = ln_b[2 * lane], bb1 = ln_b[2 * lane + 1];
    #pragma unroll 1
    for (int r = wid; r < 64; r += 4) {
        const int row = rowbase + r;
        const float2 v = *(const float2*)(z + (size_t)row * DDIM + 2 * lane);
        float s = v.x + v.y;
        float s2 = v.x * v.x + v.y * v.y;
        #pragma unroll
        for (int off = 32; off > 0; off >>= 1) {
            s  += __shfl_xor(s, off, 64);
            s2 += __shfl_xor(s2, off, 64);
        }
        const float mu = s * (1.0f / 128.0f);
        const float var = s2 * (1.0f / 128.0f) - mu * mu;
        const float rs = rsqrtf(var + LN_EPS);
        znws[(size_t)row * 64 + lane] =
            pack2((v.x - mu) * rs * g0 + bb0, (v.y - mu) * rs * g1 + bb1);
    }
}

// =====================================================================
// K1: QKV GEMM, 3-way N-split. Grid 2400 (sect = bx%3, m = bx/3), block 256.
// Round-3: B-frags from LDS again -- staged as 8 uint4 copies/thread from
// fragment-ordered g_wbf (no conversion), consumed via conflict-free
// ds_read_b128 (64 lanes x consecutive 16B). A-frags direct from global.
// K/V sections process COMPACT rows only (gather via g_inv). LDS (34.8KB)
// is reused as the transpose buffer after the MFMA loop (single-phase
// epilogue). Layouts: q [nh][320][32]; k [nh][PT16][32]; v [nh][32][CP8].
// =====================================================================
__global__ __launch_bounds__(256, 4) void k1_qkv(
    const unsigned short* __restrict__ znws, const float* __restrict__ b_qkv,
    unsigned short* __restrict__ qws, unsigned short* __restrict__ kws,
    unsigned short* __restrict__ vws)
{
    __shared__ unsigned short ldsb[17408];  // 34816B: W frags (32KB), then tr [128][132]
    const int tid = threadIdx.x;
    const int bx = blockIdx.x;
    const int sect = bx % 3;          // 0=q 1=k 2=v
    const int mbase = (bx / 3) * 128;
    const int lane = tid & 63;
    const int wid = tid >> 6;
    const int qn = lane & 15, gd = lane >> 4;

    const int cnt = __builtin_amdgcn_readfirstlane(g_cnt);
    const int PT16 = (cnt + 15) & ~15;
    const int CP8  = (cnt + 7) & ~7;
    const int stride = (sect == 0) ? LQ : ((sect == 1) ? PT16 : CP8);
    const int rows_total = NSEQ * stride;
    if (mbase >= rows_total) return;

    // stage this section's W chunk (32KB, fragment-ordered) into LDS
    {
        const uint4* src = (const uint4*)g_wbf + sect * 2048;
        uint4* dst = (uint4*)ldsb;
        #pragma unroll
        for (int i = 0; i < 8; ++i) dst[tid + i * 256] = src[tid + i * 256];
    }

    const int n0 = mbase / stride;
    const int s0 = mbase - n0 * stride;

    // A-frag source rows (compact gather for k/v sections)
    int arow[2];
    #pragma unroll
    for (int rg = 0; rg < 2; ++rg) {
        const int off = wid * 32 + rg * 16 + qn;
        int n = n0, s = s0 + off;
        while (s >= stride) { s -= stride; ++n; }
        int grow = n * LQ + ((sect == 0) ? s : g_inv[s]);
        if (mbase + off >= rows_total) grow = 0;     // guarded at store time
        arow[rg] = grow;
    }

    __syncthreads();   // W staged

    const f32x4 zero4 = {0.f, 0.f, 0.f, 0.f};
    f32x4 acc[2][8];
    #pragma unroll
    for (int rg = 0; rg < 2; ++rg)
        #pragma unroll
        for (int nt = 0; nt < 8; ++nt) acc[rg][nt] = zero4;

    #pragma unroll
    for (int kt = 0; kt < 4; ++kt) {
        FragU af[2];
        #pragma unroll
        for (int rg = 0; rg < 2; ++rg)
            af[rg].v = *(const bf16x8*)&znws[(size_t)arow[rg] * DDIM + kt * 32 + gd * 8];
        #pragma unroll
        for (int nt = 0; nt < 8; ++nt) {
            FragU bf;
            bf.v = *(const bf16x8*)&ldsb[((kt * 8 + nt) * 64 + lane) * 8];
            #pragma unroll
            for (int rg = 0; rg < 2; ++rg)
                acc[rg][nt] = __builtin_amdgcn_mfma_f32_16x16x32_bf16(af[rg].v, bf.v, acc[rg][nt], 0, 0, 0);
        }
    }

    float bq[8];
    #pragma unroll
    for (int nt = 0; nt < 8; ++nt) bq[nt] = b_qkv[sect * 128 + nt * 16 + qn];
    const float sc = (sect == 0) ? QSC2 : 1.0f;

    __syncthreads();   // all waves done reading W LDS
    unsigned short* tr = ldsb;  // [128][132] (q/k: [row][col], v: [col][row])

    #pragma unroll
    for (int rg = 0; rg < 2; ++rg) {
        #pragma unroll
        for (int r = 0; r < 4; ++r) {
            const int row = wid * 32 + rg * 16 + 4 * gd + r;
            #pragma unroll
            for (int nt = 0; nt < 8; ++nt) {
                const int col = nt * 16 + qn;
                const unsigned short val = f2bf((acc[rg][nt][r] + bq[nt]) * sc);
                if (sect < 2) tr[row * 132 + col] = val;
                else          tr[col * 132 + row] = val;
            }
        }
    }
    __syncthreads();

    // wave-per-head coalesced stores (head h = wid)
    if (sect < 2) {
        unsigned short* dst = (sect == 0) ? qws : kws;
        #pragma unroll 1
        for (int k16 = 0; k16 < 16; ++k16) {
            const int o2 = lane * 4 + k16 * 256;     // [128 rows][32 d] per head(wid)
            const int i_loc = o2 >> 5, d = o2 & 31;
            if (mbase + i_loc < rows_total) {
                int n = n0, s = s0 + i_loc;
                while (s >= stride) { s -= stride; ++n; }
                const ushort4 val = *(const ushort4*)&tr[i_loc * 132 + wid * 32 + d];
                *(ushort4*)&dst[((size_t)(n * NH + wid) * LQ + s) * DHD + d] = val;
            }
        }
    } else {
        #pragma unroll 1
        for (int k16 = 0; k16 < 16; ++k16) {
            const int o2 = lane * 4 + k16 * 256;     // [32 d][128 rows]
            const int d = o2 >> 7, i_loc = o2 & 127;
            if (mbase + i_loc < rows_total) {
                int n = n0, s = s0 + i_loc;
                while (s >= stride) { s -= stride; ++n; }
                const ushort4 val = *(const ushort4*)&tr[(wid * 32 + d) * 132 + i_loc];
                *(ushort4*)&vws[(size_t)(n * NH + wid) * (DHD * LQ) + d * CP8 + s] = val;
            }
        }
    }
}

// =====================================================================
// K2: MFMA attention over COMPACTED keys. Grid 6400: block = (n,h,
// query-fifth); 256 thr (4 waves), one 16-query tile per wave.
// Live key tiles = ceil(cnt/16); dead tiles skipped (uniform branch);
// boundary tile folds -1e30 into MFMA C. V has per-d row stride CP8.
// =====================================================================
#define KSTR 20
__global__ __launch_bounds__(256, 4) void k2_attn_mfma(
    const unsigned short* __restrict__ qws, const unsigned short* __restrict__ kws,
    const unsigned short* __restrict__ vtws, unsigned short* __restrict__ ows)
{
    __shared__ unsigned int kT[LQ * KSTR];        // 25.6 KB max
    const int tid = threadIdx.x;
    const int bx = blockIdx.x;
    const int nh = bx / 5;
    const int qs = bx - nh * 5;
    const int lane = tid & 63;
    const int wid = tid >> 6;
    const int qn = lane & 15;
    const int gd = lane >> 4;

    const int cnt = __builtin_amdgcn_readfirstlane(g_cnt);
    const int PT  = (cnt + 15) & ~15;      // live packed K rows
    const int CP8 = (cnt + 7) & ~7;        // V col stride
    const int NCH = (PT + 159) / 160;      // chunks of 10 tiles (1 or 2)

    const uint4* kp4 = (const uint4*)(kws + (size_t)nh * LQ * DHD);
    #pragma unroll 1
    for (int idx = tid; idx < PT * 4; idx += 256) {
        const int r = idx >> 2, c4 = idx & 3;
        *(uint4*)&kT[r * KSTR + 4 * c4] = kp4[idx];
    }
    __syncthreads();

    const f32x4 zero4 = {0.f, 0.f, 0.f, 0.f};
    const int alo = (((gd & 1) << 5) | qn) << 2;
    const int ahi = alo + 64;
    const bool hiT = (gd >= 2);
    const int n = nh >> 2, h = nh & 3;
    const unsigned short* vbase = vtws + (size_t)nh * DHD * LQ;  // [32 d][CP8] bf16

    const int qt = qs * 4 + wid;

    FragU qf;
    qf.v = *(const bf16x8*)(qws + ((size_t)nh * LQ + qt * 16 + qn) * DHD + 8 * gd);

    f32x4 o0 = zero4, o1 = zero4;
    float m_run = -1e30f;
    float l_run = 0.f;

    #pragma unroll 1
    for (int ch = 0; ch < NCH; ++ch) {
        const int tb = ch * 10;

        f32x4 st[10];
        #pragma unroll
        for (int kt = 0; kt < 10; ++kt) {
            const int ktg = tb + kt;
            if (ktg * 16 < cnt) {                      // live tile (uniform)
                FragU kf;
                const uint4 kv = *(const uint4*)&kT[(ktg * 16 + qn) * KSTR + 4 * gd];
                kf.u[0] = kv.x; kf.u[1] = kv.y; kf.u[2] = kv.z; kf.u[3] = kv.w;
                f32x4 c0 = zero4;
                if ((ktg + 1) * 16 > cnt) {            // boundary tile: fold -inf bias
                    const int jb = ktg * 16 + 4 * gd;
                    #pragma unroll
                    for (int r = 0; r < 4; ++r)
                        c0[r] = (jb + r < cnt) ? 0.f : -1e30f;
                }
                st[kt] = __builtin_amdgcn_mfma_f32_16x16x32_bf16(kf.v, qf.v, c0, 0, 0, 0);
            }
        }

        float mh = -1e30f;
        #pragma unroll
        for (int kt = 0; kt < 10; ++kt)
            if ((tb + kt) * 16 < cnt)
                mh = fmaxf(mh, fmaxf(fmaxf(st[kt][0], st[kt][1]), fmaxf(st[kt][2], st[kt][3])));
        mh = fmaxf(mh, __shfl_xor(mh, 16, 64));
        mh = fmaxf(mh, __shfl_xor(mh, 32, 64));
        const float m_new = fmaxf(m_run, mh);
        const float scl = __builtin_amdgcn_exp2f(m_run - m_new);
        m_run = m_new;
        l_run *= scl;
        o0 *= scl;
        o1 *= scl;

        #pragma unroll
        for (int kt = 0; kt < 10; ++kt) {
            if ((tb + kt) * 16 < cnt) {
                st[kt][0] = __builtin_amdgcn_exp2f(st[kt][0] - m_new);
                st[kt][1] = __builtin_amdgcn_exp2f(st[kt][1] - m_new);
                st[kt][2] = __builtin_amdgcn_exp2f(st[kt][2] - m_new);
                st[kt][3] = __builtin_amdgcn_exp2f(st[kt][3] - m_new);
                l_run += st[kt][0] + st[kt][1] + st[kt][2] + st[kt][3];
            } else {
                st[kt] = zero4;                        // P = 0 for dead keys
            }
        }

        #pragma unroll
        for (int kc = 0; kc < 5; ++kc) {
            if ((tb + 2 * kc) * 16 < cnt) {            // live pair (uniform)
                const int t0 = 2 * kc, t1 = 2 * kc + 1;
                const unsigned int p01a = pack2(st[t0][0], st[t0][1]);
                const unsigned int p23a = pack2(st[t0][2], st[t0][3]);
                const unsigned int p01b = pack2(st[t1][0], st[t1][1]);
                const unsigned int p23b = pack2(st[t1][2], st[t1][3]);
                FragU pa;
                {
                    const int a0 = __builtin_amdgcn_ds_bpermute(alo, (int)p01a);
                    const int b0 = __builtin_amdgcn_ds_bpermute(alo, (int)p01b);
                    const int a1 = __builtin_amdgcn_ds_bpermute(alo, (int)p23a);
                    const int b1 = __builtin_amdgcn_ds_bpermute(alo, (int)p23b);
                    const int a2 = __builtin_amdgcn_ds_bpermute(ahi, (int)p01a);
                    const int b2 = __builtin_amdgcn_ds_bpermute(ahi, (int)p01b);
                    const int a3 = __builtin_amdgcn_ds_bpermute(ahi, (int)p23a);
                    const int b3 = __builtin_amdgcn_ds_bpermute(ahi, (int)p23b);
                    pa.u[0] = (unsigned int)(hiT ? b0 : a0);
                    pa.u[1] = (unsigned int)(hiT ? b1 : a1);
                    pa.u[2] = (unsigned int)(hiT ? b2 : a2);
                    pa.u[3] = (unsigned int)(hiT ? b3 : a3);
                }
                FragU bv0, bv1;
                const int koff = ch * 160 + 32 * kc + 8 * gd;
                bv0.v = *(const bf16x8*)(vbase + (size_t)qn * CP8 + koff);
                bv1.v = *(const bf16x8*)(vbase + (size_t)(16 + qn) * CP8 + koff);
                o0 = __builtin_amdgcn_mfma_f32_16x16x32_bf16(pa.v, bv0.v, o0, 0, 0, 0);
                o1 = __builtin_amdgcn_mfma_f32_16x16x32_bf16(pa.v, bv1.v, o1, 0, 0, 0);
            }
        }
    }

    l_run += __shfl_xor(l_run, 16, 64);
    l_run += __shfl_xor(l_run, 32, 64);
    const float inv = 1.0f / l_run;

    #pragma unroll
    for (int r = 0; r < 4; ++r) {
        const int qg = qt * 16 + 4 * gd + r;
        unsigned short* orow = ows + ((size_t)(n * LQ + qg)) * DDIM + h * DHD + qn;
        orow[0]  = f2bf(o0[r] * inv);
        orow[16] = f2bf(o1[r] * inv);
    }
}

// =====================================================================
// K3: out projection + residual, MFMA. Grid 800, block 256.
// Round-3: w_out frags staged to LDS (fragment-ordered g_wbf rows
// 384-511, sect chunk 3) -> conflict-free ds_read_b128 B-frags.
// =====================================================================
__global__ __launch_bounds__(256, 4) void k3_out(
    const unsigned short* __restrict__ ows,
    const float* __restrict__ b_out, const float* __restrict__ z,
    float* __restrict__ out)
{
    __shared__ unsigned short ldsb[16384];  // 32KB W frags
    const int tid = threadIdx.x;
    const int mbase = blockIdx.x * 128;
    const int lane = tid & 63;
    const int wid = tid >> 6;
    const int qn = lane & 15, gd = lane >> 4;

    {
        const uint4* src = (const uint4*)g_wbf + 3 * 2048;
        uint4* dst = (uint4*)ldsb;
        #pragma unroll
        for (int i = 0; i < 8; ++i) dst[tid + i * 256] = src[tid + i * 256];
    }
    __syncthreads();

    const f32x4 zero4 = {0.f, 0.f, 0.f, 0.f};
    f32x4 acc[2][8];
    #pragma unroll
    for (int rg = 0; rg < 2; ++rg)
        #pragma unroll
        for (int nt = 0; nt < 8; ++nt) acc[rg][nt] = zero4;

    #pragma unroll
    for (int kt = 0; kt < 4; ++kt) {
        FragU af[2];
        #pragma unroll
        for (int rg = 0; rg < 2; ++rg)
            af[rg].v = *(const bf16x8*)&ows[
                (size_t)(mbase + wid * 32 + rg * 16 + qn) * DDIM + kt * 32 + gd * 8];
        #pragma unroll
        for (int nt = 0; nt < 8; ++nt) {
            FragU bf;
            bf.v = *(const bf16x8*)&ldsb[((kt * 8 + nt) * 64 + lane) * 8];
            #pragma unroll
            for (int rg = 0; rg < 2; ++rg)
                acc[rg][nt] = __builtin_amdgcn_mfma_f32_16x16x32_bf16(af[rg].v, bf.v, acc[rg][nt], 0, 0, 0);
        }
    }

    float bb[8];
    #pragma unroll
    for (int nt = 0; nt < 8; ++nt) bb[nt] = b_out[nt * 16 + qn];

    #pragma unroll
    for (int rg = 0; rg < 2; ++rg) {
        #pragma unroll
        for (int r = 0; r < 4; ++r) {
            const int grow = mbase + wid * 32 + rg * 16 + 4 * gd + r;
            const float* zr = z + (size_t)grow * DDIM;
            float* outr = out + (size_t)grow * DDIM;
            #pragma unroll
            for (int nt = 0; nt < 8; ++nt) {
                const int cg = nt * 16 + qn;
                outr[cg] = acc[rg][nt][r] + bb[nt] + zr[cg];
            }
        }
    }
}

extern "C" void kernel_launch(void* const* d_in, const int* in_sizes, int n_in,
                              void* d_out, int out_size, void* d_ws, size_t ws_size,
                              hipStream_t stream) {
    const float* z     = (const float*)d_in[0];
    const int*   mask  = (const int*)d_in[1];
    const float* ln_g  = (const float*)d_in[2];
    const float* ln_b  = (const float*)d_in[3];
    const float* w_qkv = (const float*)d_in[4];
    const float* b_qkv = (const float*)d_in[5];
    const float* w_out = (const float*)d_in[6];
    const float* b_out = (const float*)d_in[7];
    float* out = (float*)d_out;

    unsigned short* ws = (unsigned short*)d_ws;
    const size_t qE = (size_t)NSEQ * NH * LQ * DHD;  // 13,107,200
    unsigned short* qws = ws;
    unsigned short* kws = qws + qE;
    unsigned short* vws = kws + qE;
    unsigned short* shared_rgn = vws + qE;           // NROWS*DDIM bf16
    unsigned int*   znws = (unsigned int*)shared_rgn;
    unsigned short* ows  = shared_rgn;

    hipLaunchKernelGGL(k0_ln, dim3(NROWS / 64), dim3(256), 0, stream,
                       z, ln_g, ln_b, znws, mask, w_qkv, w_out);
    hipLaunchKernelGGL(k1_qkv, dim3(2400), dim3(256), 0, stream,
                       (const unsigned short*)znws, b_qkv, qws, kws, vws);
    hipLaunchKernelGGL(k2_attn_mfma, dim3(6400), dim3(256), 0, stream,
                       qws, kws, vws, ows);
    hipLaunchKernelGGL(k3_out, dim3(800), dim3(256), 0, stream,
                       ows, b_out, z, out);
}

// Round 4
// 207.808 us; speedup vs baseline: 1.3152x; 1.0166x over previous
//
#include <hip/hip_runtime.h>

// Problem constants: B=1, L=320, D=128, H=4, DH=32
#define LQ 320
#define NSEQ 320
#define NROWS (NSEQ*LQ)   // 102400
#define DDIM 128
#define NH 4
#define DHD 32
#define LN_EPS 1e-5f
// 1/sqrt(32) * log2(e): folded into q so QK^T scores are in log2 domain
#define QSC2 0.25508652025545527f

typedef __bf16 bf16x8 __attribute__((ext_vector_type(8)));
typedef __bf16 bf16x2 __attribute__((ext_vector_type(2)));
typedef float f32x4 __attribute__((ext_vector_type(4)));
union FragU { unsigned int u[4]; bf16x8 v; };

// key-compaction tables (mask is over keys, shared by all rows)
__device__ int g_inv[LQ];     // compact slot -> key position (pad slots -> 0)
__device__ int g_cnt;         // number of kept keys
// pre-converted bf16 weights in MFMA FRAGMENT order:
// uint4 chunk cid = ((s4*4 + kt)*8 + nt)*64 + lane holds
// W row (s4*128 + nt*16 + (lane&15)), cols kt*32 + (lane>>4)*8 .. +7.
// s4: 0,1,2 = w_qkv q/k/v chunks, 3 = w_out.
__device__ __align__(16) unsigned short g_wbf[512 * DDIM];

// native bf16 converts: compiler lowers paired casts to v_cvt_pk_bf16_f32
// (1 instr) vs the old 4-5 op bit-twiddle (m240: cast form beats hand asm).
__device__ inline unsigned short f2bf(float f) {
    return __builtin_bit_cast(unsigned short, (__bf16)f);
}
__device__ inline unsigned int pack2(float a, float b) {
    bf16x2 t;
    t[0] = (__bf16)a;
    t[1] = (__bf16)b;
    return __builtin_bit_cast(unsigned int, t);
}

// =====================================================================
// K0: LayerNorm -> zn bf16 [row][128]. Grid 1600, block 256.
// Side jobs: block 0 wave 0: mask scan -> g_inv / g_cnt;
// blocks 1..32: W fp32 -> bf16 into g_wbf in FRAGMENT order.
// =====================================================================
__global__ __launch_bounds__(256) void k0_ln(
    const float* __restrict__ z, const float* __restrict__ ln_g, const float* __restrict__ ln_b,
    unsigned int* __restrict__ znws, const int* __restrict__ mask,
    const float* __restrict__ w_qkv, const float* __restrict__ w_out)
{
    const int tid = threadIdx.x;
    const int bx = blockIdx.x;
    const int rowbase = bx * 64;
    const int lane = tid & 63;
    const int wid = tid >> 6;

    if (bx == 0) {
        if (tid < 64) {
            int carry = 0;
            #pragma unroll 1
            for (int c = 0; c < 5; ++c) {
                const int i = c * 64 + tid;
                const int m = (mask[i] > 0) ? 1 : 0;
                int v = m;
                #pragma unroll
                for (int off = 1; off < 64; off <<= 1) {
                    const int o = __shfl_up(v, off, 64);
                    if (tid >= off) v += o;
                }
                v += carry;
                if (m) g_inv[v - 1] = i;
                carry = __shfl(v, 63, 64);
            }
            if (tid == 0) g_cnt = carry;
            for (int s = carry + tid; s < LQ; s += 64) g_inv[s] = 0;  // pad slots
        }
    } else if (bx <= 32) {
        // fragment-order W conversion: one uint4 chunk per thread
        const int cid = (bx - 1) * 256 + tid;   // 0..8191
        const int l2  = cid & 63;
        const int nt  = (cid >> 6) & 7;
        const int kt  = (cid >> 9) & 3;
        const int s4  = cid >> 11;              // 0..3
        const int qn2 = l2 & 15, gd2 = l2 >> 4;
        const int row = s4 * 128 + nt * 16 + qn2;       // 0..511
        const float4* src4 = (s4 < 3) ? (const float4*)w_qkv : (const float4*)w_out;
        const int rloc = (s4 < 3) ? row : (row - 384);
        const int fi = rloc * 32 + kt * 8 + gd2 * 2;
        const float4 a = src4[fi];
        const float4 b = src4[fi + 1];
        uint4 val;
        val.x = pack2(a.x, a.y);
        val.y = pack2(a.z, a.w);
        val.z = pack2(b.x, b.y);
        val.w = pack2(b.z, b.w);
        ((uint4*)g_wbf)[cid] = val;
    }

    const float g0 = ln_g[2 * lane], g1 = ln_g[2 * lane + 1];
    const float bb0 = ln_b[2 * lane], bb1 = ln_b[2 * lane + 1];
    #pragma unroll 1
    for (int r = wid; r < 64; r += 4) {
        const int row = rowbase + r;
        const float2 v = *(const float2*)(z + (size_t)row * DDIM + 2 * lane);
        float s = v.x + v.y;
        float s2 = v.x * v.x + v.y * v.y;
        #pragma unroll
        for (int off = 32; off > 0; off >>= 1) {
            s  += __shfl_xor(s, off, 64);
            s2 += __shfl_xor(s2, off, 64);
        }
        const float mu = s * (1.0f / 128.0f);
        const float var = s2 * (1.0f / 128.0f) - mu * mu;
        const float rs = rsqrtf(var + LN_EPS);
        znws[(size_t)row * 64 + lane] =
            pack2((v.x - mu) * rs * g0 + bb0, (v.y - mu) * rs * g1 + bb1);
    }
}

// =====================================================================
// K1: QKV GEMM, 3-way N-split. Grid 2400 (sect = bx%3, m = bx/3), block 256.
// B-frags staged to LDS from fragment-ordered g_wbf (8 uint4/thread, no
// conversion), consumed via conflict-free ds_read_b128. A-frags direct
// from global. K/V sections process COMPACT rows only (gather via g_inv).
// LDS reused as transpose buffer. Epilogue conversions via v_cvt_pk;
// v-section packs 4 rows into one uint2 LDS store.
// Layouts: q [nh][320][32]; k [nh][PT16][32]; v [nh][32][CP8].
// =====================================================================
__global__ __launch_bounds__(256, 4) void k1_qkv(
    const unsigned short* __restrict__ znws, const float* __restrict__ b_qkv,
    unsigned short* __restrict__ qws, unsigned short* __restrict__ kws,
    unsigned short* __restrict__ vws)
{
    __shared__ unsigned short ldsb[17408];  // 34816B: W frags (32KB), then tr [128][132]
    const int tid = threadIdx.x;
    const int bx = blockIdx.x;
    const int sect = bx % 3;          // 0=q 1=k 2=v
    const int mbase = (bx / 3) * 128;
    const int lane = tid & 63;
    const int wid = tid >> 6;
    const int qn = lane & 15, gd = lane >> 4;

    const int cnt = __builtin_amdgcn_readfirstlane(g_cnt);
    const int PT16 = (cnt + 15) & ~15;
    const int CP8  = (cnt + 7) & ~7;
    const int stride = (sect == 0) ? LQ : ((sect == 1) ? PT16 : CP8);
    const int rows_total = NSEQ * stride;
    if (mbase >= rows_total) return;

    // stage this section's W chunk (32KB, fragment-ordered) into LDS
    {
        const uint4* src = (const uint4*)g_wbf + sect * 2048;
        uint4* dst = (uint4*)ldsb;
        #pragma unroll
        for (int i = 0; i < 8; ++i) dst[tid + i * 256] = src[tid + i * 256];
    }

    const int n0 = mbase / stride;
    const int s0 = mbase - n0 * stride;

    // A-frag source rows (compact gather for k/v sections)
    int arow[2];
    #pragma unroll
    for (int rg = 0; rg < 2; ++rg) {
        const int off = wid * 32 + rg * 16 + qn;
        int n = n0, s = s0 + off;
        while (s >= stride) { s -= stride; ++n; }
        int grow = n * LQ + ((sect == 0) ? s : g_inv[s]);
        if (mbase + off >= rows_total) grow = 0;     // guarded at store time
        arow[rg] = grow;
    }

    __syncthreads();   // W staged

    const f32x4 zero4 = {0.f, 0.f, 0.f, 0.f};
    f32x4 acc[2][8];
    #pragma unroll
    for (int rg = 0; rg < 2; ++rg)
        #pragma unroll
        for (int nt = 0; nt < 8; ++nt) acc[rg][nt] = zero4;

    #pragma unroll
    for (int kt = 0; kt < 4; ++kt) {
        FragU af[2];
        #pragma unroll
        for (int rg = 0; rg < 2; ++rg)
            af[rg].v = *(const bf16x8*)&znws[(size_t)arow[rg] * DDIM + kt * 32 + gd * 8];
        #pragma unroll
        for (int nt = 0; nt < 8; ++nt) {
            FragU bf;
            bf.v = *(const bf16x8*)&ldsb[((kt * 8 + nt) * 64 + lane) * 8];
            #pragma unroll
            for (int rg = 0; rg < 2; ++rg)
                acc[rg][nt] = __builtin_amdgcn_mfma_f32_16x16x32_bf16(af[rg].v, bf.v, acc[rg][nt], 0, 0, 0);
        }
    }

    float bq[8];
    #pragma unroll
    for (int nt = 0; nt < 8; ++nt) bq[nt] = b_qkv[sect * 128 + nt * 16 + qn];
    const float sc = (sect == 0) ? QSC2 : 1.0f;

    __syncthreads();   // all waves done reading W LDS
    unsigned short* tr = ldsb;  // [128][132] (q/k: [row][col], v: [col][row])

    if (sect < 2) {
        #pragma unroll
        for (int rg = 0; rg < 2; ++rg) {
            #pragma unroll
            for (int r = 0; r < 4; ++r) {
                const int row = wid * 32 + rg * 16 + 4 * gd + r;
                #pragma unroll
                for (int nt = 0; nt < 8; ++nt) {
                    const int col = nt * 16 + qn;
                    tr[row * 132 + col] = f2bf((acc[rg][nt][r] + bq[nt]) * sc);
                }
            }
        }
    } else {
        // v: tr[col][row], rows 4*gd..+3 contiguous -> one uint2 (4 bf16)
        #pragma unroll
        for (int rg = 0; rg < 2; ++rg) {
            const int row0 = wid * 32 + rg * 16 + 4 * gd;
            #pragma unroll
            for (int nt = 0; nt < 8; ++nt) {
                const int col = nt * 16 + qn;
                uint2 pv;
                pv.x = pack2(acc[rg][nt][0] + bq[nt], acc[rg][nt][1] + bq[nt]);
                pv.y = pack2(acc[rg][nt][2] + bq[nt], acc[rg][nt][3] + bq[nt]);
                *(uint2*)&tr[col * 132 + row0] = pv;
            }
        }
    }
    __syncthreads();

    // wave-per-head coalesced stores (head h = wid)
    if (sect < 2) {
        unsigned short* dst = (sect == 0) ? qws : kws;
        #pragma unroll 1
        for (int k16 = 0; k16 < 16; ++k16) {
            const int o2 = lane * 4 + k16 * 256;     // [128 rows][32 d] per head(wid)
            const int i_loc = o2 >> 5, d = o2 & 31;
            if (mbase + i_loc < rows_total) {
                int n = n0, s = s0 + i_loc;
                while (s >= stride) { s -= stride; ++n; }
                const ushort4 val = *(const ushort4*)&tr[i_loc * 132 + wid * 32 + d];
                *(ushort4*)&dst[((size_t)(n * NH + wid) * LQ + s) * DHD + d] = val;
            }
        }
    } else {
        #pragma unroll 1
        for (int k16 = 0; k16 < 16; ++k16) {
            const int o2 = lane * 4 + k16 * 256;     // [32 d][128 rows]
            const int d = o2 >> 7, i_loc = o2 & 127;
            if (mbase + i_loc < rows_total) {
                int n = n0, s = s0 + i_loc;
                while (s >= stride) { s -= stride; ++n; }
                const ushort4 val = *(const ushort4*)&tr[(wid * 32 + d) * 132 + i_loc];
                *(ushort4*)&vws[(size_t)(n * NH + wid) * (DHD * LQ) + d * CP8 + s] = val;
            }
        }
    }
}

// =====================================================================
// K2: MFMA attention over COMPACTED keys. Grid 6400: block = (n,h,
// query-fifth); 256 thr (4 waves), one 16-query tile per wave.
// Round-4: V frags for the whole chunk PREFETCHED up front (T14: their
// L2 latency hides under QK^T+softmax; VGPR 44 had huge headroom);
// P packing via v_cvt_pk_bf16_f32 (native casts) instead of bit-twiddle.
// Live key tiles = ceil(cnt/16); dead tiles skipped (uniform branch);
// boundary tile folds -1e30 into MFMA C. V has per-d row stride CP8.
// =====================================================================
#define KSTR 20
__global__ __launch_bounds__(256, 4) void k2_attn_mfma(
    const unsigned short* __restrict__ qws, const unsigned short* __restrict__ kws,
    const unsigned short* __restrict__ vtws, unsigned short* __restrict__ ows)
{
    __shared__ unsigned int kT[LQ * KSTR];        // 25.6 KB max
    const int tid = threadIdx.x;
    const int bx = blockIdx.x;
    const int nh = bx / 5;
    const int qs = bx - nh * 5;
    const int lane = tid & 63;
    const int wid = tid >> 6;
    const int qn = lane & 15;
    const int gd = lane >> 4;

    const int cnt = __builtin_amdgcn_readfirstlane(g_cnt);
    const int PT  = (cnt + 15) & ~15;      // live packed K rows
    const int CP8 = (cnt + 7) & ~7;        // V col stride
    const int NCH = (PT + 159) / 160;      // chunks of 10 tiles (1 or 2)

    const uint4* kp4 = (const uint4*)(kws + (size_t)nh * LQ * DHD);
    #pragma unroll 1
    for (int idx = tid; idx < PT * 4; idx += 256) {
        const int r = idx >> 2, c4 = idx & 3;
        *(uint4*)&kT[r * KSTR + 4 * c4] = kp4[idx];
    }
    __syncthreads();

    const f32x4 zero4 = {0.f, 0.f, 0.f, 0.f};
    const int alo = (((gd & 1) << 5) | qn) << 2;
    const int ahi = alo + 64;
    const bool hiT = (gd >= 2);
    const int n = nh >> 2, h = nh & 3;
    const unsigned short* vbase = vtws + (size_t)nh * DHD * LQ;  // [32 d][CP8] bf16

    const int qt = qs * 4 + wid;

    FragU qf;
    qf.v = *(const bf16x8*)(qws + ((size_t)nh * LQ + qt * 16 + qn) * DHD + 8 * gd);

    f32x4 o0 = zero4, o1 = zero4;
    float m_run = -1e30f;
    float l_run = 0.f;

    #pragma unroll 1
    for (int ch = 0; ch < NCH; ++ch) {
        const int tb = ch * 10;

        // prefetch this chunk's V fragments (independent of scores;
        // latency hides under QK^T + softmax)
        FragU vf0[5], vf1[5];
        #pragma unroll
        for (int kc = 0; kc < 5; ++kc) {
            if ((tb + 2 * kc) * 16 < cnt) {
                const int koff = ch * 160 + 32 * kc + 8 * gd;
                vf0[kc].v = *(const bf16x8*)(vbase + (size_t)qn * CP8 + koff);
                vf1[kc].v = *(const bf16x8*)(vbase + (size_t)(16 + qn) * CP8 + koff);
            }
        }

        f32x4 st[10];
        #pragma unroll
        for (int kt = 0; kt < 10; ++kt) {
            const int ktg = tb + kt;
            if (ktg * 16 < cnt) {                      // live tile (uniform)
                FragU kf;
                const uint4 kv = *(const uint4*)&kT[(ktg * 16 + qn) * KSTR + 4 * gd];
                kf.u[0] = kv.x; kf.u[1] = kv.y; kf.u[2] = kv.z; kf.u[3] = kv.w;
                f32x4 c0 = zero4;
                if ((ktg + 1) * 16 > cnt) {            // boundary tile: fold -inf bias
                    const int jb = ktg * 16 + 4 * gd;
                    #pragma unroll
                    for (int r = 0; r < 4; ++r)
                        c0[r] = (jb + r < cnt) ? 0.f : -1e30f;
                }
                st[kt] = __builtin_amdgcn_mfma_f32_16x16x32_bf16(kf.v, qf.v, c0, 0, 0, 0);
            }
        }

        float mh = -1e30f;
        #pragma unroll
        for (int kt = 0; kt < 10; ++kt)
            if ((tb + kt) * 16 < cnt)
                mh = fmaxf(mh, fmaxf(fmaxf(st[kt][0], st[kt][1]), fmaxf(st[kt][2], st[kt][3])));
        mh = fmaxf(mh, __shfl_xor(mh, 16, 64));
        mh = fmaxf(mh, __shfl_xor(mh, 32, 64));
        const float m_new = fmaxf(m_run, mh);
        const float scl = __builtin_amdgcn_exp2f(m_run - m_new);
        m_run = m_new;
        l_run *= scl;
        o0 *= scl;
        o1 *= scl;

        float ls0 = 0.f, ls1 = 0.f;
        #pragma unroll
        for (int kt = 0; kt < 10; ++kt) {
            if ((tb + kt) * 16 < cnt) {
                st[kt][0] = __builtin_amdgcn_exp2f(st[kt][0] - m_new);
                st[kt][1] = __builtin_amdgcn_exp2f(st[kt][1] - m_new);
                st[kt][2] = __builtin_amdgcn_exp2f(st[kt][2] - m_new);
                st[kt][3] = __builtin_amdgcn_exp2f(st[kt][3] - m_new);
                ls0 += st[kt][0] + st[kt][1];
                ls1 += st[kt][2] + st[kt][3];
            } else {
                st[kt] = zero4;                        // P = 0 for dead keys
            }
        }
        l_run += ls0 + ls1;

        #pragma unroll
        for (int kc = 0; kc < 5; ++kc) {
            if ((tb + 2 * kc) * 16 < cnt) {            // live pair (uniform)
                const int t0 = 2 * kc, t1 = 2 * kc + 1;
                const unsigned int p01a = pack2(st[t0][0], st[t0][1]);
                const unsigned int p23a = pack2(st[t0][2], st[t0][3]);
                const unsigned int p01b = pack2(st[t1][0], st[t1][1]);
                const unsigned int p23b = pack2(st[t1][2], st[t1][3]);
                FragU pa;
                {
                    const int a0 = __builtin_amdgcn_ds_bpermute(alo, (int)p01a);
                    const int b0 = __builtin_amdgcn_ds_bpermute(alo, (int)p01b);
                    const int a1 = __builtin_amdgcn_ds_bpermute(alo, (int)p23a);
                    const int b1 = __builtin_amdgcn_ds_bpermute(alo, (int)p23b);
                    const int a2 = __builtin_amdgcn_ds_bpermute(ahi, (int)p01a);
                    const int b2 = __builtin_amdgcn_ds_bpermute(ahi, (int)p01b);
                    const int a3 = __builtin_amdgcn_ds_bpermute(ahi, (int)p23a);
                    const int b3 = __builtin_amdgcn_ds_bpermute(ahi, (int)p23b);
                    pa.u[0] = (unsigned int)(hiT ? b0 : a0);
                    pa.u[1] = (unsigned int)(hiT ? b1 : a1);
                    pa.u[2] = (unsigned int)(hiT ? b2 : a2);
                    pa.u[3] = (unsigned int)(hiT ? b3 : a3);
                }
                o0 = __builtin_amdgcn_mfma_f32_16x16x32_bf16(pa.v, vf0[kc].v, o0, 0, 0, 0);
                o1 = __builtin_amdgcn_mfma_f32_16x16x32_bf16(pa.v, vf1[kc].v, o1, 0, 0, 0);
            }
        }
    }

    l_run += __shfl_xor(l_run, 16, 64);
    l_run += __shfl_xor(l_run, 32, 64);
    const float inv = 1.0f / l_run;

    #pragma unroll
    for (int r = 0; r < 4; ++r) {
        const int qg = qt * 16 + 4 * gd + r;
        unsigned short* orow = ows + ((size_t)(n * LQ + qg)) * DDIM + h * DHD + qn;
        orow[0]  = f2bf(o0[r] * inv);
        orow[16] = f2bf(o1[r] * inv);
    }
}

// =====================================================================
// K3: out projection + residual, MFMA. Grid 800, block 256.
// w_out frags staged to LDS (fragment-ordered g_wbf chunk 3) ->
// conflict-free ds_read_b128 B-frags.
// =====================================================================
__global__ __launch_bounds__(256, 4) void k3_out(
    const unsigned short* __restrict__ ows,
    const float* __restrict__ b_out, const float* __restrict__ z,
    float* __restrict__ out)
{
    __shared__ unsigned short ldsb[16384];  // 32KB W frags
    const int tid = threadIdx.x;
    const int mbase = blockIdx.x * 128;
    const int lane = tid & 63;
    const int wid = tid >> 6;
    const int qn = lane & 15, gd = lane >> 4;

    {
        const uint4* src = (const uint4*)g_wbf + 3 * 2048;
        uint4* dst = (uint4*)ldsb;
        #pragma unroll
        for (int i = 0; i < 8; ++i) dst[tid + i * 256] = src[tid + i * 256];
    }
    __syncthreads();

    const f32x4 zero4 = {0.f, 0.f, 0.f, 0.f};
    f32x4 acc[2][8];
    #pragma unroll
    for (int rg = 0; rg < 2; ++rg)
        #pragma unroll
        for (int nt = 0; nt < 8; ++nt) acc[rg][nt] = zero4;

    #pragma unroll
    for (int kt = 0; kt < 4; ++kt) {
        FragU af[2];
        #pragma unroll
        for (int rg = 0; rg < 2; ++rg)
            af[rg].v = *(const bf16x8*)&ows[
                (size_t)(mbase + wid * 32 + rg * 16 + qn) * DDIM + kt * 32 + gd * 8];
        #pragma unroll
        for (int nt = 0; nt < 8; ++nt) {
            FragU bf;
            bf.v = *(const bf16x8*)&ldsb[((kt * 8 + nt) * 64 + lane) * 8];
            #pragma unroll
            for (int rg = 0; rg < 2; ++rg)
                acc[rg][nt] = __builtin_amdgcn_mfma_f32_16x16x32_bf16(af[rg].v, bf.v, acc[rg][nt], 0, 0, 0);
        }
    }

    float bb[8];
    #pragma unroll
    for (int nt = 0; nt < 8; ++nt) bb[nt] = b_out[nt * 16 + qn];

    #pragma unroll
    for (int rg = 0; rg < 2; ++rg) {
        #pragma unroll
        for (int r = 0; r < 4; ++r) {
            const int grow = mbase + wid * 32 + rg * 16 + 4 * gd + r;
            const float* zr = z + (size_t)grow * DDIM;
            float* outr = out + (size_t)grow * DDIM;
            #pragma unroll
            for (int nt = 0; nt < 8; ++nt) {
                const int cg = nt * 16 + qn;
                outr[cg] = acc[rg][nt][r] + bb[nt] + zr[cg];
            }
        }
    }
}

extern "C" void kernel_launch(void* const* d_in, const int* in_sizes, int n_in,
                              void* d_out, int out_size, void* d_ws, size_t ws_size,
                              hipStream_t stream) {
    const float* z     = (const float*)d_in[0];
    const int*   mask  = (const int*)d_in[1];
    const float* ln_g  = (const float*)d_in[2];
    const float* ln_b  = (const float*)d_in[3];
    const float* w_qkv = (const float*)d_in[4];
    const float* b_qkv = (const float*)d_in[5];
    const float* w_out = (const float*)d_in[6];
    const float* b_out = (const float*)d_in[7];
    float* out = (float*)d_out;

    unsigned short* ws = (unsigned short*)d_ws;
    const size_t qE = (size_t)NSEQ * NH * LQ * DHD;  // 13,107,200
    unsigned short* qws = ws;
    unsigned short* kws = qws + qE;
    unsigned short* vws = kws + qE;
    unsigned short* shared_rgn = vws + qE;           // NROWS*DDIM bf16
    unsigned int*   znws = (unsigned int*)shared_rgn;
    unsigned short* ows  = shared_rgn;

    hipLaunchKernelGGL(k0_ln, dim3(NROWS / 64), dim3(256), 0, stream,
                       z, ln_g, ln_b, znws, mask, w_qkv, w_out);
    hipLaunchKernelGGL(k1_qkv, dim3(2400), dim3(256), 0, stream,
                       (const unsigned short*)znws, b_qkv, qws, kws, vws);
    hipLaunchKernelGGL(k2_attn_mfma, dim3(6400), dim3(256), 0, stream,
                       qws, kws, vws, ows);
    hipLaunchKernelGGL(k3_out, dim3(800), dim3(256), 0, stream,
                       ows, b_out, z, out);
}

// Round 5
// 195.565 us; speedup vs baseline: 1.3976x; 1.0626x over previous
//
#include <hip/hip_runtime.h>

// Problem constants: B=1, L=320, D=128, H=4, DH=32
#define LQ 320
#define NSEQ 320
#define NROWS (NSEQ*LQ)   // 102400
#define DDIM 128
#define NH 4
#define DHD 32
#define LN_EPS 1e-5f
// 1/sqrt(32) * log2(e): folded into q so QK^T scores are in log2 domain
#define QSC2 0.25508652025545527f

typedef __bf16 bf16x8 __attribute__((ext_vector_type(8)));
typedef __bf16 bf16x2 __attribute__((ext_vector_type(2)));
typedef float f32x4 __attribute__((ext_vector_type(4)));
typedef float f32x16 __attribute__((ext_vector_type(16)));
union FragU { unsigned int u[4]; bf16x8 v; };

// key-compaction tables (mask is over keys, shared by all rows)
__device__ int g_inv[LQ];     // compact slot -> key position (pad slots -> 0)
__device__ int g_cnt;         // number of kept keys
// pre-converted bf16 weights in MFMA FRAGMENT order:
// uint4 chunk cid = ((s4*4 + kt)*8 + nt)*64 + lane holds
// W row (s4*128 + nt*16 + (lane&15)), cols kt*32 + (lane>>4)*8 .. +7.
// s4: 0,1,2 = w_qkv q/k/v chunks, 3 = w_out.
__device__ __align__(16) unsigned short g_wbf[512 * DDIM];

// native bf16 converts: compiler lowers paired casts to v_cvt_pk_bf16_f32
__device__ inline unsigned short f2bf(float f) {
    return __builtin_bit_cast(unsigned short, (__bf16)f);
}
__device__ inline unsigned int pack2(float a, float b) {
    bf16x2 t;
    t[0] = (__bf16)a;
    t[1] = (__bf16)b;
    return __builtin_bit_cast(unsigned int, t);
}
// 2x2 lane-block transpose: a <- [a.lo | b.lo], b <- [a.hi | b.hi]
__device__ inline void pl32swap(unsigned int &a, unsigned int &b) {
    asm volatile("v_permlane32_swap_b32 %0, %1" : "+v"(a), "+v"(b));
}

// =====================================================================
// K0: LayerNorm -> zn bf16 [row][128]. Grid 1600, block 256.
// Side jobs: block 0 wave 0: mask scan -> g_inv / g_cnt;
// blocks 1..32: W fp32 -> bf16 into g_wbf in FRAGMENT order.
// =====================================================================
__global__ __launch_bounds__(256) void k0_ln(
    const float* __restrict__ z, const float* __restrict__ ln_g, const float* __restrict__ ln_b,
    unsigned int* __restrict__ znws, const int* __restrict__ mask,
    const float* __restrict__ w_qkv, const float* __restrict__ w_out)
{
    const int tid = threadIdx.x;
    const int bx = blockIdx.x;
    const int rowbase = bx * 64;
    const int lane = tid & 63;
    const int wid = tid >> 6;

    if (bx == 0) {
        if (tid < 64) {
            int carry = 0;
            #pragma unroll 1
            for (int c = 0; c < 5; ++c) {
                const int i = c * 64 + tid;
                const int m = (mask[i] > 0) ? 1 : 0;
                int v = m;
                #pragma unroll
                for (int off = 1; off < 64; off <<= 1) {
                    const int o = __shfl_up(v, off, 64);
                    if (tid >= off) v += o;
                }
                v += carry;
                if (m) g_inv[v - 1] = i;
                carry = __shfl(v, 63, 64);
            }
            if (tid == 0) g_cnt = carry;
            for (int s = carry + tid; s < LQ; s += 64) g_inv[s] = 0;  // pad slots
        }
    } else if (bx <= 32) {
        // fragment-order W conversion: one uint4 chunk per thread
        const int cid = (bx - 1) * 256 + tid;   // 0..8191
        const int l2  = cid & 63;
        const int nt  = (cid >> 6) & 7;
        const int kt  = (cid >> 9) & 3;
        const int s4  = cid >> 11;              // 0..3
        const int qn2 = l2 & 15, gd2 = l2 >> 4;
        const int row = s4 * 128 + nt * 16 + qn2;       // 0..511
        const float4* src4 = (s4 < 3) ? (const float4*)w_qkv : (const float4*)w_out;
        const int rloc = (s4 < 3) ? row : (row - 384);
        const int fi = rloc * 32 + kt * 8 + gd2 * 2;
        const float4 a = src4[fi];
        const float4 b = src4[fi + 1];
        uint4 val;
        val.x = pack2(a.x, a.y);
        val.y = pack2(a.z, a.w);
        val.z = pack2(b.x, b.y);
        val.w = pack2(b.z, b.w);
        ((uint4*)g_wbf)[cid] = val;
    }

    const float g0 = ln_g[2 * lane], g1 = ln_g[2 * lane + 1];
    const float bb0 = ln_b[2 * lane], bb1 = ln_b[2 * lane + 1];
    #pragma unroll 1
    for (int r = wid; r < 64; r += 4) {
        const int row = rowbase + r;
        const float2 v = *(const float2*)(z + (size_t)row * DDIM + 2 * lane);
        float s = v.x + v.y;
        float s2 = v.x * v.x + v.y * v.y;
        #pragma unroll
        for (int off = 32; off > 0; off >>= 1) {
            s  += __shfl_xor(s, off, 64);
            s2 += __shfl_xor(s2, off, 64);
        }
        const float mu = s * (1.0f / 128.0f);
        const float var = s2 * (1.0f / 128.0f) - mu * mu;
        const float rs = rsqrtf(var + LN_EPS);
        znws[(size_t)row * 64 + lane] =
            pack2((v.x - mu) * rs * g0 + bb0, (v.y - mu) * rs * g1 + bb1);
    }
}

// =====================================================================
// K1: QKV GEMM, 3-way N-split. Grid 2400 (sect = bx%3, m = bx/3), block 256.
// B-frags staged to LDS from fragment-ordered g_wbf; A-frags direct from
// global. K/V sections process COMPACT rows only (gather via g_inv).
// Round-5 ripple: K stride rounded to 32 (PT32) so k2's 32-wide tiles
// are fully initialized (pad slots = row-0 K, killed by -1e30 bias).
// Layouts: q [nh][320][32]; k [nh][PT32][32]; v [nh][32][CP8].
// =====================================================================
__global__ __launch_bounds__(256, 4) void k1_qkv(
    const unsigned short* __restrict__ znws, const float* __restrict__ b_qkv,
    unsigned short* __restrict__ qws, unsigned short* __restrict__ kws,
    unsigned short* __restrict__ vws)
{
    __shared__ unsigned short ldsb[17408];  // 34816B: W frags (32KB), then tr [128][132]
    const int tid = threadIdx.x;
    const int bx = blockIdx.x;
    const int sect = bx % 3;          // 0=q 1=k 2=v
    const int mbase = (bx / 3) * 128;
    const int lane = tid & 63;
    const int wid = tid >> 6;
    const int qn = lane & 15, gd = lane >> 4;

    const int cnt = __builtin_amdgcn_readfirstlane(g_cnt);
    const int PT32 = (cnt + 31) & ~31;
    const int CP8  = (cnt + 7) & ~7;
    const int stride = (sect == 0) ? LQ : ((sect == 1) ? PT32 : CP8);
    const int rows_total = NSEQ * stride;
    if (mbase >= rows_total) return;

    // stage this section's W chunk (32KB, fragment-ordered) into LDS
    {
        const uint4* src = (const uint4*)g_wbf + sect * 2048;
        uint4* dst = (uint4*)ldsb;
        #pragma unroll
        for (int i = 0; i < 8; ++i) dst[tid + i * 256] = src[tid + i * 256];
    }

    const int n0 = mbase / stride;
    const int s0 = mbase - n0 * stride;

    // A-frag source rows (compact gather for k/v sections)
    int arow[2];
    #pragma unroll
    for (int rg = 0; rg < 2; ++rg) {
        const int off = wid * 32 + rg * 16 + qn;
        int n = n0, s = s0 + off;
        while (s >= stride) { s -= stride; ++n; }
        int grow = n * LQ + ((sect == 0) ? s : g_inv[s]);
        if (mbase + off >= rows_total) grow = 0;     // guarded at store time
        arow[rg] = grow;
    }

    __syncthreads();   // W staged

    const f32x4 zero4 = {0.f, 0.f, 0.f, 0.f};
    f32x4 acc[2][8];
    #pragma unroll
    for (int rg = 0; rg < 2; ++rg)
        #pragma unroll
        for (int nt = 0; nt < 8; ++nt) acc[rg][nt] = zero4;

    #pragma unroll
    for (int kt = 0; kt < 4; ++kt) {
        FragU af[2];
        #pragma unroll
        for (int rg = 0; rg < 2; ++rg)
            af[rg].v = *(const bf16x8*)&znws[(size_t)arow[rg] * DDIM + kt * 32 + gd * 8];
        #pragma unroll
        for (int nt = 0; nt < 8; ++nt) {
            FragU bf;
            bf.v = *(const bf16x8*)&ldsb[((kt * 8 + nt) * 64 + lane) * 8];
            #pragma unroll
            for (int rg = 0; rg < 2; ++rg)
                acc[rg][nt] = __builtin_amdgcn_mfma_f32_16x16x32_bf16(af[rg].v, bf.v, acc[rg][nt], 0, 0, 0);
        }
    }

    float bq[8];
    #pragma unroll
    for (int nt = 0; nt < 8; ++nt) bq[nt] = b_qkv[sect * 128 + nt * 16 + qn];
    const float sc = (sect == 0) ? QSC2 : 1.0f;

    __syncthreads();   // all waves done reading W LDS
    unsigned short* tr = ldsb;  // [128][132] (q/k: [row][col], v: [col][row])

    if (sect < 2) {
        #pragma unroll
        for (int rg = 0; rg < 2; ++rg) {
            #pragma unroll
            for (int r = 0; r < 4; ++r) {
                const int row = wid * 32 + rg * 16 + 4 * gd + r;
                #pragma unroll
                for (int nt = 0; nt < 8; ++nt) {
                    const int col = nt * 16 + qn;
                    tr[row * 132 + col] = f2bf((acc[rg][nt][r] + bq[nt]) * sc);
                }
            }
        }
    } else {
        // v: tr[col][row], rows 4*gd..+3 contiguous -> one uint2 (4 bf16)
        #pragma unroll
        for (int rg = 0; rg < 2; ++rg) {
            const int row0 = wid * 32 + rg * 16 + 4 * gd;
            #pragma unroll
            for (int nt = 0; nt < 8; ++nt) {
                const int col = nt * 16 + qn;
                uint2 pv;
                pv.x = pack2(acc[rg][nt][0] + bq[nt], acc[rg][nt][1] + bq[nt]);
                pv.y = pack2(acc[rg][nt][2] + bq[nt], acc[rg][nt][3] + bq[nt]);
                *(uint2*)&tr[col * 132 + row0] = pv;
            }
        }
    }
    __syncthreads();

    // wave-per-head coalesced stores (head h = wid)
    if (sect < 2) {
        unsigned short* dst = (sect == 0) ? qws : kws;
        #pragma unroll 1
        for (int k16 = 0; k16 < 16; ++k16) {
            const int o2 = lane * 4 + k16 * 256;     // [128 rows][32 d] per head(wid)
            const int i_loc = o2 >> 5, d = o2 & 31;
            if (mbase + i_loc < rows_total) {
                int n = n0, s = s0 + i_loc;
                while (s >= stride) { s -= stride; ++n; }
                const ushort4 val = *(const ushort4*)&tr[i_loc * 132 + wid * 32 + d];
                *(ushort4*)&dst[((size_t)(n * NH + wid) * LQ + s) * DHD + d] = val;
            }
        }
    } else {
        #pragma unroll 1
        for (int k16 = 0; k16 < 16; ++k16) {
            const int o2 = lane * 4 + k16 * 256;     // [32 d][128 rows]
            const int d = o2 >> 7, i_loc = o2 & 127;
            if (mbase + i_loc < rows_total) {
                int n = n0, s = s0 + i_loc;
                while (s >= stride) { s -= stride; ++n; }
                const ushort4 val = *(const ushort4*)&tr[(wid * 32 + d) * 132 + i_loc];
                *(ushort4*)&vws[(size_t)(n * NH + wid) * (DHD * LQ) + d * CP8 + s] = val;
            }
        }
    }
}

// =====================================================================
// K2: MFMA attention, round-5: 32x32x16 MFMA, ZERO LDS, zero bpermute.
// Grid 2560 (bx = nh*2 + half), block 320 (5 waves); each wave owns a
// 32-query tile. Per 32-key tile: st = mfma32(K,Q) x2 (scores[k][q],
// col=lane&31=q); P->PV A-operand via 8 cvt_pk + 4 permlane32_swap
// (T12 2x2 lane-block transpose). K/Q/V frags direct from global
// (planes L1/L2-resident). Online softmax per tile with defer-max
// (T13, THR=8, log2 domain). Boundary tile folds -1e30 into MFMA C;
// pad K slots (< PT32) hold row-0 K, killed exactly by the bias.
// =====================================================================
__global__ __launch_bounds__(320, 4) void k2_attn_mfma(
    const unsigned short* __restrict__ qws, const unsigned short* __restrict__ kws,
    const unsigned short* __restrict__ vtws, unsigned short* __restrict__ ows)
{
    const int tid = threadIdx.x;
    const int bx = blockIdx.x;
    const int nh = bx >> 1;
    const int lane = tid & 63;
    const int wid = tid >> 6;              // 0..4
    const int qt = (bx & 1) * 5 + wid;     // 32-query tile, 0..9
    const int qc = lane & 31;              // score col (q); O col (d)
    const int hf = lane >> 5;

    const int cnt = __builtin_amdgcn_readfirstlane(g_cnt);
    const int PT32 = (cnt + 31) & ~31;
    const int CP8  = (cnt + 7) & ~7;
    const int NT   = PT32 >> 5;

    const int n = nh >> 2, h = nh & 3;
    const unsigned short* kb = kws + (size_t)nh * LQ * DHD + hf * 8;
    const unsigned short* vb = vtws + (size_t)nh * DHD * LQ + (size_t)qc * CP8 + hf * 8;
    const unsigned short* qp = qws + ((size_t)nh * LQ + qt * 32 + qc) * DHD + hf * 8;

    FragU qf1, qf2;
    qf1.v = *(const bf16x8*)qp;
    qf2.v = *(const bf16x8*)(qp + 16);

    f32x16 o;
    #pragma unroll
    for (int r = 0; r < 16; ++r) o[r] = 0.f;
    float m_run = -1e30f, l_run = 0.f;

    #pragma unroll 1
    for (int kt = 0; kt < NT; ++kt) {
        const unsigned short* kr = kb + (size_t)(kt * 32 + qc) * DHD;
        FragU kf1, kf2, vf1, vf2;
        kf1.v = *(const bf16x8*)kr;
        kf2.v = *(const bf16x8*)(kr + 16);
        vf1.v = *(const bf16x8*)(vb + kt * 32);        // V[k 0..15 of tile][d]
        vf2.v = *(const bf16x8*)(vb + kt * 32 + 16);   // V[k 16..31][d]

        f32x16 c0;
        #pragma unroll
        for (int r = 0; r < 16; ++r) c0[r] = 0.f;
        if ((kt + 1) * 32 > cnt) {                     // boundary: fold -inf bias
            #pragma unroll
            for (int r = 0; r < 16; ++r) {
                const int krow = kt * 32 + (r & 3) + 8 * (r >> 2) + 4 * hf;
                c0[r] = (krow < cnt) ? 0.f : -1e30f;
            }
        }
        f32x16 st = __builtin_amdgcn_mfma_f32_32x32x16_bf16(kf1.v, qf1.v, c0, 0, 0, 0);
        st = __builtin_amdgcn_mfma_f32_32x32x16_bf16(kf2.v, qf2.v, st, 0, 0, 0);

        float mh = st[0];
        #pragma unroll
        for (int r = 1; r < 16; ++r) mh = fmaxf(mh, st[r]);
        mh = fmaxf(mh, __shfl_xor(mh, 32, 64));
        if (!__all(mh <= m_run + 8.0f)) {              // defer-max (log2 domain)
            const float m_new = fmaxf(m_run, mh);
            const float scl = __builtin_amdgcn_exp2f(m_run - m_new);
            l_run *= scl;
            #pragma unroll
            for (int r = 0; r < 16; ++r) o[r] *= scl;
            m_run = m_new;
        }
        #pragma unroll
        for (int r = 0; r < 16; ++r) st[r] = __builtin_amdgcn_exp2f(st[r] - m_run);
        l_run += (((st[0] + st[1]) + (st[2] + st[3])) + ((st[4] + st[5]) + (st[6] + st[7])))
               + (((st[8] + st[9]) + (st[10] + st[11])) + ((st[12] + st[13]) + (st[14] + st[15])));

        // P -> A-operand fragments (rows=q, k = hf*8..+7 per lane)
        unsigned int a01 = pack2(st[0], st[1]), a23 = pack2(st[2], st[3]);
        unsigned int a45 = pack2(st[4], st[5]), a67 = pack2(st[6], st[7]);
        pl32swap(a01, a45);   // a01 = k(+0,+1), a45 = k(+4,+5) per half
        pl32swap(a23, a67);
        FragU pa1;
        pa1.u[0] = a01; pa1.u[1] = a23; pa1.u[2] = a45; pa1.u[3] = a67;
        o = __builtin_amdgcn_mfma_f32_32x32x16_bf16(pa1.v, vf1.v, o, 0, 0, 0);

        unsigned int b01 = pack2(st[8], st[9]),  b23 = pack2(st[10], st[11]);
        unsigned int b45 = pack2(st[12], st[13]), b67 = pack2(st[14], st[15]);
        pl32swap(b01, b45);
        pl32swap(b23, b67);
        FragU pa2;
        pa2.u[0] = b01; pa2.u[1] = b23; pa2.u[2] = b45; pa2.u[3] = b67;
        o = __builtin_amdgcn_mfma_f32_32x32x16_bf16(pa2.v, vf2.v, o, 0, 0, 0);
    }

    l_run += __shfl_xor(l_run, 32, 64);
    const float inv = 1.0f / l_run;

    #pragma unroll
    for (int r = 0; r < 16; ++r) {
        const int qloc = (r & 3) + 8 * (r >> 2) + 4 * hf;
        const float iv = __shfl(inv, qloc, 64);        // l for row-q of this reg
        const int qg = qt * 32 + qloc;
        ows[((size_t)(n * LQ + qg)) * DDIM + h * DHD + qc] = f2bf(o[r] * iv);
    }
}

// =====================================================================
// K3: out projection + residual, MFMA. Grid 800, block 256.
// w_out frags staged to LDS (fragment-ordered g_wbf chunk 3) ->
// conflict-free ds_read_b128 B-frags.
// =====================================================================
__global__ __launch_bounds__(256, 4) void k3_out(
    const unsigned short* __restrict__ ows,
    const float* __restrict__ b_out, const float* __restrict__ z,
    float* __restrict__ out)
{
    __shared__ unsigned short ldsb[16384];  // 32KB W frags
    const int tid = threadIdx.x;
    const int mbase = blockIdx.x * 128;
    const int lane = tid & 63;
    const int wid = tid >> 6;
    const int qn = lane & 15, gd = lane >> 4;

    {
        const uint4* src = (const uint4*)g_wbf + 3 * 2048;
        uint4* dst = (uint4*)ldsb;
        #pragma unroll
        for (int i = 0; i < 8; ++i) dst[tid + i * 256] = src[tid + i * 256];
    }
    __syncthreads();

    const f32x4 zero4 = {0.f, 0.f, 0.f, 0.f};
    f32x4 acc[2][8];
    #pragma unroll
    for (int rg = 0; rg < 2; ++rg)
        #pragma unroll
        for (int nt = 0; nt < 8; ++nt) acc[rg][nt] = zero4;

    #pragma unroll
    for (int kt = 0; kt < 4; ++kt) {
        FragU af[2];
        #pragma unroll
        for (int rg = 0; rg < 2; ++rg)
            af[rg].v = *(const bf16x8*)&ows[
                (size_t)(mbase + wid * 32 + rg * 16 + qn) * DDIM + kt * 32 + gd * 8];
        #pragma unroll
        for (int nt = 0; nt < 8; ++nt) {
            FragU bf;
            bf.v = *(const bf16x8*)&ldsb[((kt * 8 + nt) * 64 + lane) * 8];
            #pragma unroll
            for (int rg = 0; rg < 2; ++rg)
                acc[rg][nt] = __builtin_amdgcn_mfma_f32_16x16x32_bf16(af[rg].v, bf.v, acc[rg][nt], 0, 0, 0);
        }
    }

    float bb[8];
    #pragma unroll
    for (int nt = 0; nt < 8; ++nt) bb[nt] = b_out[nt * 16 + qn];

    #pragma unroll
    for (int rg = 0; rg < 2; ++rg) {
        #pragma unroll
        for (int r = 0; r < 4; ++r) {
            const int grow = mbase + wid * 32 + rg * 16 + 4 * gd + r;
            const float* zr = z + (size_t)grow * DDIM;
            float* outr = out + (size_t)grow * DDIM;
            #pragma unroll
            for (int nt = 0; nt < 8; ++nt) {
                const int cg = nt * 16 + qn;
                outr[cg] = acc[rg][nt][r] + bb[nt] + zr[cg];
            }
        }
    }
}

extern "C" void kernel_launch(void* const* d_in, const int* in_sizes, int n_in,
                              void* d_out, int out_size, void* d_ws, size_t ws_size,
                              hipStream_t stream) {
    const float* z     = (const float*)d_in[0];
    const int*   mask  = (const int*)d_in[1];
    const float* ln_g  = (const float*)d_in[2];
    const float* ln_b  = (const float*)d_in[3];
    const float* w_qkv = (const float*)d_in[4];
    const float* b_qkv = (const float*)d_in[5];
    const float* w_out = (const float*)d_in[6];
    const float* b_out = (const float*)d_in[7];
    float* out = (float*)d_out;

    unsigned short* ws = (unsigned short*)d_ws;
    const size_t qE = (size_t)NSEQ * NH * LQ * DHD;  // 13,107,200
    unsigned short* qws = ws;
    unsigned short* kws = qws + qE;
    unsigned short* vws = kws + qE;
    unsigned short* shared_rgn = vws + qE;           // NROWS*DDIM bf16
    unsigned int*   znws = (unsigned int*)shared_rgn;
    unsigned short* ows  = shared_rgn;

    hipLaunchKernelGGL(k0_ln, dim3(NROWS / 64), dim3(256), 0, stream,
                       z, ln_g, ln_b, znws, mask, w_qkv, w_out);
    hipLaunchKernelGGL(k1_qkv, dim3(2400), dim3(256), 0, stream,
                       (const unsigned short*)znws, b_qkv, qws, kws, vws);
    hipLaunchKernelGGL(k2_attn_mfma, dim3(2560), dim3(320), 0, stream,
                       qws, kws, vws, ows);
    hipLaunchKernelGGL(k3_out, dim3(800), dim3(256), 0, stream,
                       ows, b_out, z, out);
}